// Round 1
// baseline (875.487 us; speedup 1.0000x reference)
//
#include <hip/hip_runtime.h>
#include <math.h>
#include <limits.h>

// Problem constants (from reference): B=64, N=2048 predictions, M=64 gt boxes.
#define Bb 64
#define Nn 2048
#define Mm 64

// ---------------------------------------------------------------------------
// Kernel 1: cost[b][j][i] = -ps[b][j][gs[b][i]] + sum_k |pb[b][j][k]-gb[b][i][k]|
// f32, sequential sum order ((a0+a1)+a2)+a3 to match XLA-CPU lowering.
// Fully coalesced: lane = i (fastest dim of output).
// ---------------------------------------------------------------------------
__global__ __launch_bounds__(256) void cost_kernel(
    const float* __restrict__ ps,   // (B,N,2)
    const float* __restrict__ pb,   // (B,N,4)
    const int*   __restrict__ gs,   // (B,M)
    const float* __restrict__ gb,   // (B,M,4)
    float* __restrict__ out)        // (B,N,M)
{
    const int e = blockIdx.x * 256 + threadIdx.x;   // < 2^23, fits int
    const int i = e & 63;
    const int j = (e >> 6) & 2047;
    const int b = e >> 17;          // N*M = 2^17
    const int g = gs[b * Mm + i];
    const float psv = ps[((b * Nn) + j) * 2 + g];
    const float4 pb4 = ((const float4*)pb)[b * Nn + j];
    const float4 gb4 = ((const float4*)gb)[b * Mm + i];
    float l1 = fabsf(pb4.x - gb4.x);
    l1 += fabsf(pb4.y - gb4.y);
    l1 += fabsf(pb4.z - gb4.z);
    l1 += fabsf(pb4.w - gb4.w);
    out[e] = (-psv) + l1;           // presence + l1 (commutative, exact)
}

// ---------------------------------------------------------------------------
// Kernel 2: replicate the reference's (buggy) assignment loop exactly.
// Key observation: mv/wy in the reference are local copies never written back,
// so minv stays INF and way stays 0. Effective algorithm per row i:
//   j0 = 0; p[0] = i
//   loop: used[j0]=1; i0=p[j0];
//         j1 = first-argmin over free j of ((cost64[i0][j] - u[i0]) - v[j])
//         delta = that min; for used j: u[p[j]] += delta, v[j] -= delta
//         j0 = j1; if p[j0]==0: break
//   p[j0] = i           (augment with way==0 collapses to this)
// All f64 ops replicated in the same order for bitwise-identical decisions.
// One block per batch, 256 threads, 8 columns/thread.
// ---------------------------------------------------------------------------
struct HState {
    double u[Mm + 1];        // row potentials
    double v[Nn + 1];        // col potentials
    int    p[Nn + 1];        // col -> row assignment (0 = free)
    int    used[Nn + 1];
    int    used_list[Nn + 1];
    float4 gbv[Mm];
    int    gsv[Mm];
    int    col4row[Mm];
    // scalar broadcast slots
    double sh_u;             // u[i0]
    double pv[4];            // per-wave reduction partials
    int    pi[4];
    float4 sh_gb;
    int    sh_g;
    int    sh_j0;
    int    sh_done;
    int    n_used;
};

__global__ __launch_bounds__(256) void hungarian_kernel(
    const float* __restrict__ ps, const float* __restrict__ pb,
    const int* __restrict__ gs, const float* __restrict__ gb,
    float* __restrict__ out_row, float* __restrict__ out_col)
{
    __shared__ HState s;
    const int b = blockIdx.x;
    const int t = threadIdx.x;
    const float2* psb = (const float2*)(ps + (size_t)b * Nn * 2);
    const float4* pbb = (const float4*)(pb + (size_t)b * Nn * 4);

    for (int j = t; j <= Nn; j += 256) { s.v[j] = 0.0; s.p[j] = 0; }
    for (int k = t; k <= Mm; k += 256) s.u[k] = 0.0;
    if (t < Mm) {
        s.gsv[t] = gs[b * Mm + t];
        s.gbv[t] = ((const float4*)gb)[b * Mm + t];
    }
    __syncthreads();

    for (int i = 1; i <= Mm; ++i) {
        for (int j = t; j <= Nn; j += 256) s.used[j] = 0;
        if (t == 0) { s.p[0] = i; s.sh_j0 = 0; s.n_used = 0; s.sh_done = 0; }
        __syncthreads();

        for (;;) {
            if (t == 0) {
                const int j0 = s.sh_j0;
                s.used[j0] = 1;
                s.used_list[s.n_used++] = j0;
                const int i0 = s.p[j0];
                s.sh_u  = s.u[i0];
                s.sh_g  = s.gsv[i0 - 1];
                s.sh_gb = s.gbv[i0 - 1];
            }
            __syncthreads();
            const double u0  = s.sh_u;
            const int    g   = s.sh_g;
            const float4 gb4 = s.sh_gb;

            double bv = __builtin_inf();
            int bj = INT_MAX;
            #pragma unroll
            for (int k = 0; k < 8; ++k) {
                const int j = 1 + t + (k << 8);     // ascending within thread
                if (!s.used[j]) {
                    const float2 ps2 = psb[j - 1];
                    const float pres = -(g == 0 ? ps2.x : ps2.y);
                    const float4 pb4 = pbb[j - 1];
                    float l1 = fabsf(pb4.x - gb4.x);
                    l1 += fabsf(pb4.y - gb4.y);
                    l1 += fabsf(pb4.z - gb4.z);
                    l1 += fabsf(pb4.w - gb4.w);
                    const double cur = ((double)(pres + l1) - u0) - s.v[j];
                    if (cur < bv) { bv = cur; bj = j; }   // strict <: first-min
                }
            }
            // 64-lane wave argmin, lexicographic (val, idx) => numpy first-min
            #pragma unroll
            for (int off = 32; off > 0; off >>= 1) {
                const double ov = __shfl_down(bv, off);
                const int    oj = __shfl_down(bj, off);
                if (ov < bv || (ov == bv && oj < bj)) { bv = ov; bj = oj; }
            }
            if ((t & 63) == 0) { s.pv[t >> 6] = bv; s.pi[t >> 6] = bj; }
            __syncthreads();
            if (t == 0) {
                double fv = s.pv[0]; int fj = s.pi[0];
                #pragma unroll
                for (int w = 1; w < 4; ++w) {
                    const double ov = s.pv[w]; const int oj = s.pi[w];
                    if (ov < fv || (ov == fv && oj < fj)) { fv = ov; fj = oj; }
                }
                const double dl = fv;                 // delta = min cur
                for (int q = 0; q < s.n_used; ++q) {  // distinct rows: order-free
                    const int jq = s.used_list[q];
                    s.u[s.p[jq]] += dl;
                    s.v[jq] -= dl;
                }
                s.sh_j0 = fj;
                s.sh_done = (s.p[fj] == 0);
            }
            __syncthreads();
            if (s.sh_done) break;
        }
        if (t == 0) s.p[s.sh_j0] = i;   // augment with way==0 collapses to this
        __syncthreads();
    }

    // col4row[p[j]-1] = j-1 for assigned columns
    for (int j = 1 + t; j <= Nn; j += 256) {
        const int pi = s.p[j];
        if (pi > 0) s.col4row[pi - 1] = j - 1;
    }
    __syncthreads();
    // row_ind = sorted pred indices; col_ind = gt index ordered by pred index.
    // Distinct pred indices -> rank by counting smaller values.
    if (t < Mm) {
        const int my = s.col4row[t];
        int rank = 0;
        #pragma unroll 4
        for (int q = 0; q < Mm; ++q) rank += (s.col4row[q] < my);
        out_row[b * Mm + rank] = (float)my;
        out_col[b * Mm + rank] = (float)t;
    }
}

extern "C" void kernel_launch(void* const* d_in, const int* in_sizes, int n_in,
                              void* d_out, int out_size, void* d_ws, size_t ws_size,
                              hipStream_t stream) {
    const float* ps = (const float*)d_in[0];   // (64,2048,2) f32
    const float* pb = (const float*)d_in[1];   // (64,2048,4) f32
    const int*   gs = (const int*)d_in[2];     // (64,64) i32
    const float* gb = (const float*)d_in[3];   // (64,64,4) f32
    float* out = (float*)d_out;
    float* out_row = out + (size_t)Bb * Nn * Mm;          // 8388608
    float* out_col = out_row + Bb * Mm;                    // +4096

    cost_kernel<<<(Bb * Nn * Mm) / 256, 256, 0, stream>>>(ps, pb, gs, gb, out);
    hungarian_kernel<<<Bb, 256, 0, stream>>>(ps, pb, gs, gb, out_row, out_col);
}

// Round 2
// 674.402 us; speedup vs baseline: 1.2982x; 1.2982x over previous
//
#include <hip/hip_runtime.h>
#include <math.h>
#include <limits.h>

// Problem constants (from reference): B=64, N=2048 predictions, M=64 gt boxes.
#define Bb 64
#define Nn 2048
#define Mm 64

// ---------------------------------------------------------------------------
// Kernel 1: cost[b][j][i] = -ps[b][j][gs[b][i]] + sum_k |pb[b][j][k]-gb[b][i][k]|
// (unchanged from round 1 — passed with absmax 0)
// ---------------------------------------------------------------------------
__global__ __launch_bounds__(256) void cost_kernel(
    const float* __restrict__ ps,   // (B,N,2)
    const float* __restrict__ pb,   // (B,N,4)
    const int*   __restrict__ gs,   // (B,M)
    const float* __restrict__ gb,   // (B,M,4)
    float* __restrict__ out)        // (B,N,M)
{
    const int e = blockIdx.x * 256 + threadIdx.x;
    const int i = e & 63;
    const int j = (e >> 6) & 2047;
    const int b = e >> 17;
    const int g = gs[b * Mm + i];
    const float psv = ps[((b * Nn) + j) * 2 + g];
    const float4 pb4 = ((const float4*)pb)[b * Nn + j];
    const float4 gb4 = ((const float4*)gb)[b * Mm + i];
    float l1 = fabsf(pb4.x - gb4.x);
    l1 += fabsf(pb4.y - gb4.y);
    l1 += fabsf(pb4.z - gb4.z);
    l1 += fabsf(pb4.w - gb4.w);
    out[e] = (-psv) + l1;
}

// ---------------------------------------------------------------------------
// Kernel 2: reference's (buggy) JV loop, restructured for latency:
//  - deferred potential updates (sequential per-element suffix adds at row end,
//    bitwise-identical f64 order to the reference's iterative adds)
//  - used[] folded into vv[] (-inf sentinel => cur=+inf, excluded by strict <)
//  - all-threads redundant final argmin from double-buffered LDS partials
//  => exactly ONE __syncthreads() per chain iteration (+2 per row).
// Chain heads are distinct rows => T <= 64.
// ---------------------------------------------------------------------------
__global__ __launch_bounds__(256) void hungarian_kernel(
    const float* __restrict__ ps, const float* __restrict__ pb,
    const int* __restrict__ gs, const float* __restrict__ gb,
    float* __restrict__ out_row, float* __restrict__ out_col)
{
    __shared__ double s_u[Mm + 1];       // row potentials (true values)
    __shared__ double s_v[Nn + 1];       // col potentials (true values)
    __shared__ double s_vv[Nn + 1];      // scan copy: ==v[j], or -inf while used this row
    __shared__ int    s_p[Nn + 1];       // col -> row (0 = free)
    __shared__ int    s_used[Mm + 8];    // chain columns this row
    __shared__ double s_delta[Mm + 8];   // delta per chain iteration
    __shared__ double s_pv[2][4];        // per-wave argmin partials (parity-buffered)
    __shared__ int    s_pi[2][4];
    __shared__ float4 s_gbv[Mm];
    __shared__ int    s_gsv[Mm];
    __shared__ int    s_c4r[Mm];

    const int b = blockIdx.x;
    const int t = threadIdx.x;
    const float2* psb = (const float2*)(ps + (size_t)b * Nn * 2);
    const float4* pbb = (const float4*)(pb + (size_t)b * Nn * 4);

    for (int j = t; j <= Nn; j += 256) { s_v[j] = 0.0; s_vv[j] = 0.0; s_p[j] = 0; }
    if (t <= Mm) s_u[t] = 0.0;
    if (t < Mm) {
        s_gsv[t] = gs[b * Mm + t];
        s_gbv[t] = ((const float4*)gb)[b * Mm + t];
    }
    __syncthreads();

    for (int i = 1; i <= Mm; ++i) {
        int T = 0, fj = 0, par = 0;
        int i0 = i;                       // head row; == p[fj] for fj>0, i for fj==0
        for (;;) {
            const double u0  = s_u[i0];   // row-start value: untouched mid-row (deferred)
            const int    g   = s_gsv[i0 - 1];
            const float4 gb4 = s_gbv[i0 - 1];
            if (t == 0) s_used[T] = fj;

            double bv = __builtin_inf();
            int bj = INT_MAX;
            #pragma unroll
            for (int k = 0; k < 8; ++k) {
                const int j = 1 + t + (k << 8);
                if (j == fj) {                       // newly-used column: mark & skip
                    s_vv[j] = -__builtin_inf();
                    continue;
                }
                const double vj = s_vv[j];           // ==v[j] for free cols (bit-exact)
                const float2 ps2 = psb[j - 1];
                const float pres = -(g == 0 ? ps2.x : ps2.y);
                const float4 pb4 = pbb[j - 1];
                float l1 = fabsf(pb4.x - gb4.x);
                l1 += fabsf(pb4.y - gb4.y);
                l1 += fabsf(pb4.z - gb4.z);
                l1 += fabsf(pb4.w - gb4.w);
                const double cur = ((double)(pres + l1) - u0) - vj;  // +inf if used
                if (cur < bv) { bv = cur; bj = j; }  // strict <: first-min
            }
            #pragma unroll
            for (int off = 32; off > 0; off >>= 1) {
                const double ov = __shfl_down(bv, off);
                const int    oj = __shfl_down(bj, off);
                if (ov < bv || (ov == bv && oj < bj)) { bv = ov; bj = oj; }
            }
            if ((t & 63) == 0) { s_pv[par][t >> 6] = bv; s_pi[par][t >> 6] = bj; }
            __syncthreads();                         // the ONE barrier per iteration

            double fv = s_pv[par][0]; fj = s_pi[par][0];
            #pragma unroll
            for (int w = 1; w < 4; ++w) {
                const double ov = s_pv[par][w]; const int oj = s_pi[par][w];
                if (ov < fv || (ov == fv && oj < fj)) { fv = ov; fj = oj; }
            }
            if (t == 0) s_delta[T] = fv;
            T++; par ^= 1;
            const int pfj = s_p[fj];                 // uniform broadcast
            if (pfj == 0) break;
            i0 = pfj;
        }
        __syncthreads();                             // s_delta complete, safe to read
        if (t < T) {
            const int jq = s_used[t];
            const int iq = jq ? s_p[jq] : i;         // p[0] == i conceptually
            double au = s_u[iq];
            double av = s_v[jq];
            for (int k = t; k < T; ++k) {            // sequential adds: bitwise = ref
                const double d = s_delta[k];
                au += d; av -= d;
            }
            s_u[iq] = au; s_v[jq] = av;
            if (jq) s_vv[jq] = av;                   // un-mark: restore true v
        }
        if (t == 0) s_p[fj] = i;                     // augment (way==0 collapse)
        __syncthreads();
    }

    // col4row[p[j]-1] = j-1 for assigned columns
    for (int j = 1 + t; j <= Nn; j += 256) {
        const int pi = s_p[j];
        if (pi > 0) s_c4r[pi - 1] = j - 1;
    }
    __syncthreads();
    // row_ind = sorted pred indices; col_ind = gt index ordered by pred index.
    if (t < Mm) {
        const int my = s_c4r[t];
        int rank = 0;
        #pragma unroll 4
        for (int q = 0; q < Mm; ++q) rank += (s_c4r[q] < my);
        out_row[b * Mm + rank] = (float)my;
        out_col[b * Mm + rank] = (float)t;
    }
}

extern "C" void kernel_launch(void* const* d_in, const int* in_sizes, int n_in,
                              void* d_out, int out_size, void* d_ws, size_t ws_size,
                              hipStream_t stream) {
    const float* ps = (const float*)d_in[0];   // (64,2048,2) f32
    const float* pb = (const float*)d_in[1];   // (64,2048,4) f32
    const int*   gs = (const int*)d_in[2];     // (64,64) i32
    const float* gb = (const float*)d_in[3];   // (64,64,4) f32
    float* out = (float*)d_out;
    float* out_row = out + (size_t)Bb * Nn * Mm;          // 8388608
    float* out_col = out_row + Bb * Mm;                    // +4096

    cost_kernel<<<(Bb * Nn * Mm) / 256, 256, 0, stream>>>(ps, pb, gs, gb, out);
    hungarian_kernel<<<Bb, 256, 0, stream>>>(ps, pb, gs, gb, out_row, out_col);
}

// Round 3
// 559.923 us; speedup vs baseline: 1.5636x; 1.2045x over previous
//
#include <hip/hip_runtime.h>
#include <math.h>
#include <limits.h>

// Problem constants (from reference): B=64, N=2048 predictions, M=64 gt boxes.
#define Bb 64
#define Nn 2048
#define Mm 64

// ---------------------------------------------------------------------------
// Kernel 1: cost[b][j][i] (B,N,M) — unchanged (passes bitwise, absmax 0).
// ---------------------------------------------------------------------------
__global__ __launch_bounds__(256) void cost_kernel(
    const float* __restrict__ ps, const float* __restrict__ pb,
    const int* __restrict__ gs, const float* __restrict__ gb,
    float* __restrict__ out)
{
    const int e = blockIdx.x * 256 + threadIdx.x;
    const int i = e & 63;
    const int j = (e >> 6) & 2047;
    const int b = e >> 17;
    const int g = gs[b * Mm + i];
    const float psv = ps[((b * Nn) + j) * 2 + g];
    const float4 pb4 = ((const float4*)pb)[b * Nn + j];
    const float4 gb4 = ((const float4*)gb)[b * Mm + i];
    float l1 = fabsf(pb4.x - gb4.x);
    l1 += fabsf(pb4.y - gb4.y);
    l1 += fabsf(pb4.z - gb4.z);
    l1 += fabsf(pb4.w - gb4.w);
    out[e] = (-psv) + l1;
}

// ---------------------------------------------------------------------------
// Kernel 1b: transposed cost cT[b][i][j] (B,M,N) into workspace — identical
// float expression (bitwise-equal values), coalesced on j.
// ---------------------------------------------------------------------------
__global__ __launch_bounds__(256) void costT_kernel(
    const float* __restrict__ ps, const float* __restrict__ pb,
    const int* __restrict__ gs, const float* __restrict__ gb,
    float* __restrict__ cT)
{
    const int e = blockIdx.x * 256 + threadIdx.x;
    const int j = e & 2047;
    const int i = (e >> 11) & 63;
    const int b = e >> 17;
    const int g = gs[b * Mm + i];
    const float2 p2 = ((const float2*)ps)[b * Nn + j];
    const float psv = (g == 0) ? p2.x : p2.y;
    const float4 pb4 = ((const float4*)pb)[b * Nn + j];
    const float4 gb4 = ((const float4*)gb)[b * Mm + i];
    float l1 = fabsf(pb4.x - gb4.x);
    l1 += fabsf(pb4.y - gb4.y);
    l1 += fabsf(pb4.z - gb4.z);
    l1 += fabsf(pb4.w - gb4.w);
    cT[e] = (-psv) + l1;
}

// 64-lane lexicographic (value,index) min via DPP; result lands in lane 63.
// Invalid source lanes receive (+inf, INT_MAX) via update_dpp's `old` operand
// => merge is a no-op there. Predicate = strict lex-min = numpy first-argmin.
#define DPP_MERGE(CTRL)                                                         \
  {                                                                             \
    const long long bb_ = __double_as_longlong(bv);                             \
    const int lo_ = __builtin_amdgcn_update_dpp(0, (int)bb_, CTRL, 0xf, 0xf, false);            \
    const int hi_ = __builtin_amdgcn_update_dpp(0x7ff00000, (int)(bb_ >> 32), CTRL, 0xf, 0xf, false); \
    const int oj_ = __builtin_amdgcn_update_dpp(0x7fffffff, bj, CTRL, 0xf, 0xf, false);         \
    const double ov_ = __longlong_as_double(((long long)hi_ << 32) | (unsigned int)lo_);        \
    if (ov_ < bv || (ov_ == bv && oj_ < bj)) { bv = ov_; bj = oj_; }            \
  }

// ---------------------------------------------------------------------------
// Kernel 2: reference's (buggy) JV loop. One block per batch, 256 threads.
// Per chain-iteration: coalesced cT-row scan (f32), register v-copies,
// DPP wave argmin, ONE barrier, ballot-based p[] lookup. Potential updates
// deferred to row end with bitwise-sequential f64 suffix adds.
// ---------------------------------------------------------------------------
__global__ __launch_bounds__(256) void hungarian_kernel(
    const float* __restrict__ cmat,   // per-batch cost base (see strides)
    long rbstride,                     // elements between batches
    long rstride,                      // elements between rows i
    long cstride,                      // elements between cols j
    float* __restrict__ out_row, float* __restrict__ out_col)
{
    __shared__ double s_v[Nn + 1];      // true col potentials
    __shared__ double s_delta[Mm + 8];  // delta per chain iteration
    __shared__ int    s_j[Mm + 8];      // col entered per chain iteration
    __shared__ double s_pv[2][4];       // per-wave argmin partials (parity buf)
    __shared__ int    s_pi[2][4];
    __shared__ int    s_c4r[Mm];

    const int b = blockIdx.x;
    const int t = threadIdx.x;
    const int lane = t & 63;
    const float* __restrict__ cb = cmat + (long)b * rbstride;
    const double INF = __builtin_inf();

    for (int j = t; j <= Nn; j += 256) s_v[j] = 0.0;
    __syncthreads();

    double vv[8];                       // scan copies of v for my 8 columns
    #pragma unroll
    for (int k = 0; k < 8; ++k) vv[k] = 0.0;
    double my_u = 0.0;                  // u[lane+1], replicated per wave
    int my_col = 0;                     // col assigned to row lane+1 (0 = none)
    int par = 0;

    for (int i = 1; i <= Mm; ++i) {
        int T = 0;
        int fj = 0;                     // col entered this iteration (0 = virtual)
        int i0 = i;                     // row to scan
        int my_pos = -1;                // my row's position in this chain

        for (;;) {
            if (t == 0) s_j[T] = fj;
            if (fj && ((fj - 1) & 255) == t) vv[(fj - 1) >> 8] = -INF; // mark used
            if (lane + 1 == i0) my_pos = T;

            const double u0 = __shfl(my_u, i0 - 1, 64);
            const float* __restrict__ row = cb + (long)(i0 - 1) * rstride;

            double bv = INF;
            int bj = INT_MAX;
            #pragma unroll
            for (int k = 0; k < 8; ++k) {
                const int j = 1 + t + (k << 8);          // ascending in k
                const float c = row[(long)(j - 1) * cstride];
                const double cur = ((double)c - u0) - vv[k];  // +inf if used
                if (cur < bv) { bv = cur; bj = j; }      // strict <: first-min
            }
            DPP_MERGE(0x111)   // row_shr:1
            DPP_MERGE(0x112)   // row_shr:2
            DPP_MERGE(0x114)   // row_shr:4
            DPP_MERGE(0x118)   // row_shr:8
            DPP_MERGE(0x142)   // row_bcast:15
            DPP_MERGE(0x143)   // row_bcast:31
            if (lane == 63) { s_pv[par][t >> 6] = bv; s_pi[par][t >> 6] = bj; }
            __syncthreads();                             // the ONE barrier/iter

            double fv = s_pv[par][0]; fj = s_pi[par][0];
            #pragma unroll
            for (int w = 1; w < 4; ++w) {
                const double ov = s_pv[par][w]; const int oj = s_pi[par][w];
                if (ov < fv || (ov == fv && oj < fj)) { fv = ov; fj = oj; }
            }
            if (t == 0) s_delta[T] = fv;
            T++; par ^= 1;

            const unsigned long long m = __ballot(my_col == fj); // p[fj] lookup
            if (m == 0) break;                            // free col -> done
            i0 = (int)__builtin_ctzll(m) + 1;             // owning row
        }

        __syncthreads();   // t0's s_delta/s_j visible to all waves
        // u[row at chain pos q] += delta_q, delta_{q+1}, ... (sequential = ref)
        if (my_pos >= 0) {
            double au = my_u;
            for (int k = my_pos; k < T; ++k) au += s_delta[k];
            my_u = au;
        }
        // v[col entered at pos q] -= delta_q, ... (sequential = ref); skip j=0
        if (t < T) {
            const int jq = s_j[t];
            if (jq) {
                double nv = s_v[jq];
                for (int k = t; k < T; ++k) nv -= s_delta[k];
                s_v[jq] = nv;
            }
        }
        if (lane == i - 1) my_col = fj;                  // augment (way==0)
        __syncthreads();   // s_v updates visible
        #pragma unroll
        for (int k = 0; k < 8; ++k) vv[k] = s_v[1 + t + (k << 8)]; // un-mark
    }

    // Emit row_ind (sorted pred idx) / col_ind (gt idx ordered by pred idx).
    if (t < Mm) s_c4r[t] = my_col - 1;   // wave 0: row t+1 -> 0-based pred idx
    __syncthreads();
    if (t < Mm) {
        const int my = s_c4r[t];
        int rank = 0;
        #pragma unroll 4
        for (int q = 0; q < Mm; ++q) rank += (s_c4r[q] < my);
        out_row[b * Mm + rank] = (float)my;
        out_col[b * Mm + rank] = (float)t;
    }
}

extern "C" void kernel_launch(void* const* d_in, const int* in_sizes, int n_in,
                              void* d_out, int out_size, void* d_ws, size_t ws_size,
                              hipStream_t stream) {
    const float* ps = (const float*)d_in[0];   // (64,2048,2) f32
    const float* pb = (const float*)d_in[1];   // (64,2048,4) f32
    const int*   gs = (const int*)d_in[2];     // (64,64) i32
    const float* gb = (const float*)d_in[3];   // (64,64,4) f32
    float* out = (float*)d_out;
    float* out_row = out + (size_t)Bb * Nn * Mm;          // 8388608
    float* out_col = out_row + Bb * Mm;                    // +4096

    cost_kernel<<<(Bb * Nn * Mm) / 256, 256, 0, stream>>>(ps, pb, gs, gb, out);

    const size_t ct_elems = (size_t)Bb * Mm * Nn;
    const bool use_ws = ws_size >= ct_elems * sizeof(float);
    if (use_ws) {
        float* cT = (float*)d_ws;
        costT_kernel<<<(Bb * Mm * Nn) / 256, 256, 0, stream>>>(ps, pb, gs, gb, cT);
        // cT[b][i][j]: batch stride M*N, row stride N, col stride 1 (coalesced)
        hungarian_kernel<<<Bb, 256, 0, stream>>>(cT, (long)Mm * Nn, (long)Nn, 1L,
                                                 out_row, out_col);
    } else {
        // Fallback: read c[b][j][i] from d_out: batch stride N*M, row stride 1,
        // col stride M (uncoalesced but L2-resident).
        hungarian_kernel<<<Bb, 256, 0, stream>>>(out, (long)Nn * Mm, 1L, (long)Mm,
                                                 out_row, out_col);
    }
}

// Round 4
// 382.616 us; speedup vs baseline: 2.2882x; 1.4634x over previous
//
#include <hip/hip_runtime.h>
#include <math.h>
#include <limits.h>

// Problem constants (from reference): B=64, N=2048 predictions, M=64 gt boxes.
#define Bb 64
#define Nn 2048
#define Mm 64

// ---------------------------------------------------------------------------
// Kernel 1: cost[b][j][i] (B,N,M) — unchanged (passes bitwise, absmax 0).
// ---------------------------------------------------------------------------
__global__ __launch_bounds__(256) void cost_kernel(
    const float* __restrict__ ps, const float* __restrict__ pb,
    const int* __restrict__ gs, const float* __restrict__ gb,
    float* __restrict__ out)
{
    const int e = blockIdx.x * 256 + threadIdx.x;
    const int i = e & 63;
    const int j = (e >> 6) & 2047;
    const int b = e >> 17;
    const int g = gs[b * Mm + i];
    const float psv = ps[((b * Nn) + j) * 2 + g];
    const float4 pb4 = ((const float4*)pb)[b * Nn + j];
    const float4 gb4 = ((const float4*)gb)[b * Mm + i];
    float l1 = fabsf(pb4.x - gb4.x);
    l1 += fabsf(pb4.y - gb4.y);
    l1 += fabsf(pb4.z - gb4.z);
    l1 += fabsf(pb4.w - gb4.w);
    out[e] = (-psv) + l1;
}

// ---------------------------------------------------------------------------
// Kernel 1b: transposed cost cT[b][i][j] (B,M,N) into workspace.
// ---------------------------------------------------------------------------
__global__ __launch_bounds__(256) void costT_kernel(
    const float* __restrict__ ps, const float* __restrict__ pb,
    const int* __restrict__ gs, const float* __restrict__ gb,
    float* __restrict__ cT)
{
    const int e = blockIdx.x * 256 + threadIdx.x;
    const int j = e & 2047;
    const int i = (e >> 11) & 63;
    const int b = e >> 17;
    const int g = gs[b * Mm + i];
    const float2 p2 = ((const float2*)ps)[b * Nn + j];
    const float psv = (g == 0) ? p2.x : p2.y;
    const float4 pb4 = ((const float4*)pb)[b * Nn + j];
    const float4 gb4 = ((const float4*)gb)[b * Mm + i];
    float l1 = fabsf(pb4.x - gb4.x);
    l1 += fabsf(pb4.y - gb4.y);
    l1 += fabsf(pb4.z - gb4.z);
    l1 += fabsf(pb4.w - gb4.w);
    cT[e] = (-psv) + l1;
}

// 64-lane lexicographic (value,index) min via DPP; result lands in lane 63.
#define DPP_MERGE(CTRL)                                                         \
  {                                                                             \
    const long long bb_ = __double_as_longlong(bv);                             \
    const int lo_ = __builtin_amdgcn_update_dpp(0, (int)bb_, CTRL, 0xf, 0xf, false);            \
    const int hi_ = __builtin_amdgcn_update_dpp(0x7ff00000, (int)(bb_ >> 32), CTRL, 0xf, 0xf, false); \
    const int oj_ = __builtin_amdgcn_update_dpp(0x7fffffff, bj, CTRL, 0xf, 0xf, false);         \
    const double ov_ = __longlong_as_double(((long long)hi_ << 32) | (unsigned int)lo_);        \
    if (ov_ < bv || (ov_ == bv && oj_ < bj)) { bv = ov_; bj = oj_; }            \
  }

// Barrier that drains LDS ops only (lgkmcnt=0) and leaves global/VMEM
// (speculative prefetches) in flight: vmcnt=63, expcnt=7, lgkmcnt=0 -> 0xC07F.
__device__ __forceinline__ void barrier_lgkm() {
    asm volatile("" ::: "memory");
    __builtin_amdgcn_s_waitcnt(0xC07F);
    __builtin_amdgcn_s_barrier();
    asm volatile("" ::: "memory");
}

struct alignas(16) Pt { double v; int j; int pad; };

// Touch one 8KB cost row (64 lanes x 4B at 128B stride) -> warms L1/L2.
// Destination is a throwaway LDS dump; data is never read (vmcnt never waited).
__device__ __forceinline__ void prefetch_row(const float* rowbase, void* ldsdump) {
    const int lane = threadIdx.x & 63;
    __builtin_amdgcn_global_load_lds(
        (const __attribute__((address_space(1))) void*)(rowbase + lane * 32),
        (__attribute__((address_space(3))) void*)ldsdump, 4, 0, 0);
}

// ---------------------------------------------------------------------------
// Kernel 2: reference's (buggy) JV loop. One block per batch, 256 threads.
// RS/CS = row/col strides (compile-time). PF = speculative row prefetch.
// ---------------------------------------------------------------------------
template<long RS, long CS, bool PF>
__global__ __launch_bounds__(256) void hungarian_kernel(
    const float* __restrict__ cmat,
    float* __restrict__ out_row, float* __restrict__ out_col)
{
    __shared__ double s_v[Nn + 1];      // true col potentials
    __shared__ double s_delta[Mm + 8];  // delta per chain iteration
    __shared__ int    s_j[Mm + 8];      // col entered per chain iteration
    __shared__ Pt     s_part[2][4];     // per-wave argmin partials (parity buf)
    __shared__ int    s_c4r[Mm];
    __shared__ float  s_dump[4][64];    // prefetch dump (never read)

    const int b = blockIdx.x;
    const int t = threadIdx.x;
    const int lane = t & 63;
    const int wave = t >> 6;
    const float* __restrict__ cb = cmat + (long)b * ((long)Mm * Nn);
    const double INF = __builtin_inf();

    for (int j = t; j <= Nn; j += 256) s_v[j] = 0.0;
    if (PF && wave == 0) prefetch_row(cb, &s_dump[0][0]);   // head row of i=1
    __syncthreads();

    double vv[8];                       // scan copies of v for my 8 columns
    #pragma unroll
    for (int k = 0; k < 8; ++k) vv[k] = 0.0;
    double my_u = 0.0;                  // u[lane+1], replicated per wave
    int my_col = 0;                     // col assigned to row lane+1 (0 = none)
    int par = 0;

    for (int i = 1; i <= Mm; ++i) {
        int T = 0;
        int fj = 0;                     // col entered this iteration (0 = virtual)
        int i0 = i;                     // row to scan
        int my_pos = -1;                // my row's position in this chain

        for (;;) {
            if (t == 0) s_j[T] = fj;
            if (fj && ((fj - 1) & 255) == t) vv[(fj - 1) >> 8] = -INF; // mark used
            if (lane + 1 == i0) my_pos = T;

            const double u0 = __shfl(my_u, i0 - 1, 64);
            const float* __restrict__ row = cb + (long)(i0 - 1) * RS;

            double bv = INF;
            int bj = INT_MAX;
            #pragma unroll
            for (int k = 0; k < 8; ++k) {
                const int j = 1 + t + (k << 8);          // ascending in k
                const float c = row[(long)(j - 1) * CS];
                const double cur = ((double)c - u0) - vv[k];  // +inf if used
                if (cur < bv) { bv = cur; bj = j; }      // strict <: first-min
            }
            DPP_MERGE(0x111)   // row_shr:1
            DPP_MERGE(0x112)   // row_shr:2
            DPP_MERGE(0x114)   // row_shr:4
            DPP_MERGE(0x118)   // row_shr:8
            DPP_MERGE(0x142)   // row_bcast:15
            DPP_MERGE(0x143)   // row_bcast:31
            if (lane == 63) { s_part[par][wave].v = bv; s_part[par][wave].j = bj; }

            if (PF) {
                // Speculative: warm the candidate next row (winner's is right).
                const int fjw = __builtin_amdgcn_readlane(bj, 63);
                const unsigned long long mw = __ballot(my_col == fjw);
                if (mw != 0ULL)
                    prefetch_row(cb + (long)__builtin_ctzll(mw) * RS, &s_dump[wave][0]);
            }
            barrier_lgkm();                              // lgkm-only: prefetch stays in flight

            Pt pa = s_part[par][0];
            double fv = pa.v; fj = pa.j;
            #pragma unroll
            for (int w = 1; w < 4; ++w) {
                const Pt pb_ = s_part[par][w];
                if (pb_.v < fv || (pb_.v == fv && pb_.j < fj)) { fv = pb_.v; fj = pb_.j; }
            }
            if (t == 0) s_delta[T] = fv;
            T++; par ^= 1;

            const unsigned long long m = __ballot(my_col == fj); // p[fj] lookup
            if (m == 0ULL) {                              // free col -> chain done
                if (PF && i < Mm && wave == 0)
                    prefetch_row(cb + (long)i * RS, &s_dump[0][0]);  // next head row
                break;
            }
            i0 = (int)__builtin_ctzll(m) + 1;             // owning row
        }

        barrier_lgkm();   // t0's s_delta/s_j visible to all waves
        // u[row at chain pos q] += delta_q ... delta_{T-1} (sequential = ref)
        if (my_pos >= 0) {
            double au = my_u;
            for (int k = my_pos; k < T; ++k) au += s_delta[k];
            my_u = au;
        }
        // v[col entered at pos q] -= delta_q ... (sequential = ref); skip j=0
        if (t < T) {
            const int jq = s_j[t];
            if (jq) {
                double nv = s_v[jq];
                for (int k = t; k < T; ++k) nv -= s_delta[k];
                s_v[jq] = nv;
            }
        }
        if (lane == i - 1) my_col = fj;                  // augment (way==0)
        barrier_lgkm();   // s_v updates visible
        #pragma unroll
        for (int k = 0; k < 8; ++k) vv[k] = s_v[1 + t + (k << 8)]; // un-mark
    }

    // Emit row_ind (sorted pred idx) / col_ind (gt idx ordered by pred idx).
    if (t < Mm) s_c4r[t] = my_col - 1;   // wave 0: row t+1 -> 0-based pred idx
    __syncthreads();
    if (t < Mm) {
        const int my = s_c4r[t];
        int rank = 0;
        #pragma unroll 4
        for (int q = 0; q < Mm; ++q) rank += (s_c4r[q] < my);
        out_row[b * Mm + rank] = (float)my;
        out_col[b * Mm + rank] = (float)t;
    }
}

extern "C" void kernel_launch(void* const* d_in, const int* in_sizes, int n_in,
                              void* d_out, int out_size, void* d_ws, size_t ws_size,
                              hipStream_t stream) {
    const float* ps = (const float*)d_in[0];   // (64,2048,2) f32
    const float* pb = (const float*)d_in[1];   // (64,2048,4) f32
    const int*   gs = (const int*)d_in[2];     // (64,64) i32
    const float* gb = (const float*)d_in[3];   // (64,64,4) f32
    float* out = (float*)d_out;
    float* out_row = out + (size_t)Bb * Nn * Mm;          // 8388608
    float* out_col = out_row + Bb * Mm;                    // +4096

    cost_kernel<<<(Bb * Nn * Mm) / 256, 256, 0, stream>>>(ps, pb, gs, gb, out);

    const size_t ct_elems = (size_t)Bb * Mm * Nn;
    if (ws_size >= ct_elems * sizeof(float)) {
        float* cT = (float*)d_ws;
        costT_kernel<<<(Bb * Mm * Nn) / 256, 256, 0, stream>>>(ps, pb, gs, gb, cT);
        // cT[b][i][j]: row stride N, col stride 1 (coalesced), prefetch on
        hungarian_kernel<Nn, 1L, true><<<Bb, 256, 0, stream>>>(cT, out_row, out_col);
    } else {
        // Fallback: read c[b][j][i] from d_out: row stride 1, col stride M
        hungarian_kernel<1L, Mm, false><<<Bb, 256, 0, stream>>>(out, out_row, out_col);
    }
}

// Round 5
// 373.877 us; speedup vs baseline: 2.3416x; 1.0234x over previous
//
#include <hip/hip_runtime.h>
#include <math.h>
#include <limits.h>

// Problem constants (from reference): B=64, N=2048 predictions, M=64 gt boxes.
#define Bb 64
#define Nn 2048
#define Mm 64

__device__ __forceinline__ float cost1(const float4 pb4, const float4 gb4,
                                       const float2 p2, const int g) {
    const float psv = (g == 0) ? p2.x : p2.y;
    float l1 = fabsf(pb4.x - gb4.x);
    l1 += fabsf(pb4.y - gb4.y);
    l1 += fabsf(pb4.z - gb4.z);
    l1 += fabsf(pb4.w - gb4.w);
    return (-psv) + l1;
}

// ---------------------------------------------------------------------------
// Dual-layout cost kernel: out[b][j][i] (B,N,M) and cT[b][i][j] (B,M,N),
// all stores float4. Tile = one batch, 64 j, all 64 i. Grid = Bb*(Nn/64).
// Float expression identical to rounds 1-4 (absmax 0).
// ---------------------------------------------------------------------------
template<bool WRITE_T>
__global__ __launch_bounds__(256) void cost_dual_kernel(
    const float* __restrict__ ps, const float* __restrict__ pb,
    const int* __restrict__ gs, const float* __restrict__ gb,
    float* __restrict__ out, float* __restrict__ cT)
{
    const int blk = blockIdx.x;
    const int b  = blk >> 5;            // 32 tiles per batch
    const int j0 = (blk & 31) << 6;     // tile j start
    const int t  = threadIdx.x;
    const int sub = t & 15;
    const int grp = t >> 4;             // 0..15

    // ---- Layout A: out[b][j][i4..i4+3], float4 over i ----
    {
        const int i4 = sub << 2;
        const int4   g4 = ((const int4*)(gs + b * Mm))[sub];
        const float4 gbq0 = ((const float4*)gb)[b * Mm + i4 + 0];
        const float4 gbq1 = ((const float4*)gb)[b * Mm + i4 + 1];
        const float4 gbq2 = ((const float4*)gb)[b * Mm + i4 + 2];
        const float4 gbq3 = ((const float4*)gb)[b * Mm + i4 + 3];
        #pragma unroll
        for (int r = 0; r < 4; ++r) {
            const int j = j0 + grp + (r << 4);
            const float2 p2  = ((const float2*)ps)[b * Nn + j];
            const float4 pb4 = ((const float4*)pb)[b * Nn + j];
            float4 o;
            o.x = cost1(pb4, gbq0, p2, g4.x);
            o.y = cost1(pb4, gbq1, p2, g4.y);
            o.z = cost1(pb4, gbq2, p2, g4.z);
            o.w = cost1(pb4, gbq3, p2, g4.w);
            ((float4*)(out + (((size_t)b * Nn + j) << 6)))[sub] = o;
        }
    }
    // ---- Layout B: cT[b][i][j4..j4+3], float4 over j ----
    if (WRITE_T) {
        const int j4 = j0 + (sub << 2);
        const float4 pbq0 = ((const float4*)pb)[b * Nn + j4 + 0];
        const float4 pbq1 = ((const float4*)pb)[b * Nn + j4 + 1];
        const float4 pbq2 = ((const float4*)pb)[b * Nn + j4 + 2];
        const float4 pbq3 = ((const float4*)pb)[b * Nn + j4 + 3];
        const float2 psq0 = ((const float2*)ps)[b * Nn + j4 + 0];
        const float2 psq1 = ((const float2*)ps)[b * Nn + j4 + 1];
        const float2 psq2 = ((const float2*)ps)[b * Nn + j4 + 2];
        const float2 psq3 = ((const float2*)ps)[b * Nn + j4 + 3];
        #pragma unroll
        for (int r = 0; r < 4; ++r) {
            const int i = grp + (r << 4);
            const int g = gs[b * Mm + i];
            const float4 gb4 = ((const float4*)gb)[b * Mm + i];
            float4 o;
            o.x = cost1(pbq0, gb4, psq0, g);
            o.y = cost1(pbq1, gb4, psq1, g);
            o.z = cost1(pbq2, gb4, psq2, g);
            o.w = cost1(pbq3, gb4, psq3, g);
            ((float4*)(cT + (((size_t)b * Mm + i) << 11)))[j4 >> 2] = o;
        }
    }
}

// 64-lane lexicographic (value,index) min via DPP; result lands in lane 63.
#define DPP_MERGE(CTRL)                                                         \
  {                                                                             \
    const long long bb_ = __double_as_longlong(bv);                             \
    const int lo_ = __builtin_amdgcn_update_dpp(0, (int)bb_, CTRL, 0xf, 0xf, false);            \
    const int hi_ = __builtin_amdgcn_update_dpp(0x7ff00000, (int)(bb_ >> 32), CTRL, 0xf, 0xf, false); \
    const int oj_ = __builtin_amdgcn_update_dpp(0x7fffffff, bj, CTRL, 0xf, 0xf, false);         \
    const double ov_ = __longlong_as_double(((long long)hi_ << 32) | (unsigned int)lo_);        \
    if (ov_ < bv || (ov_ == bv && oj_ < bj)) { bv = ov_; bj = oj_; }            \
  }

// Barrier that drains LDS ops only (lgkmcnt=0) and leaves global/VMEM
// (speculative prefetches) in flight: vmcnt=63, expcnt=7, lgkmcnt=0 -> 0xC07F.
__device__ __forceinline__ void barrier_lgkm() {
    asm volatile("" ::: "memory");
    __builtin_amdgcn_s_waitcnt(0xC07F);
    __builtin_amdgcn_s_barrier();
    asm volatile("" ::: "memory");
}

struct alignas(16) Pt { double v; int j; int pad; };

// Touch one 8KB cost row (64 lanes x 4B at 128B stride) -> warms L1/L2.
__device__ __forceinline__ void prefetch_row(const float* rowbase, void* ldsdump) {
    const int lane = threadIdx.x & 63;
    __builtin_amdgcn_global_load_lds(
        (const __attribute__((address_space(1))) void*)(rowbase + lane * 32),
        (__attribute__((address_space(3))) void*)ldsdump, 4, 0, 0);
}

// ---------------------------------------------------------------------------
// Kernel 2: reference's (buggy) JV loop. One block per batch, 256 threads.
// Thread t owns cols j in [8t+1, 8t+8] (2x dwordx4 loads when CS==1).
// In-thread tournament (keep-left-on-tie = first-min), DPP wave argmin,
// one lgkm-barrier per iteration, speculative next-row prefetch.
// ---------------------------------------------------------------------------
template<long RS, long CS, bool PF>
__global__ __launch_bounds__(256) void hungarian_kernel(
    const float* __restrict__ cmat,
    float* __restrict__ out_row, float* __restrict__ out_col)
{
    __shared__ double s_v[Nn + 1];      // true col potentials
    __shared__ double s_delta[Mm + 8];  // delta per chain iteration
    __shared__ int    s_j[Mm + 8];      // col entered per chain iteration
    __shared__ Pt     s_part[2][4];     // per-wave argmin partials (parity buf)
    __shared__ int    s_c4r[Mm];
    __shared__ float  s_dump[4][64];    // prefetch dump (never read)

    const int b = blockIdx.x;
    const int t = threadIdx.x;
    const int lane = t & 63;
    const int wave = t >> 6;
    const float* __restrict__ cb = cmat + (long)b * ((long)Mm * Nn);
    const double INF = __builtin_inf();

    for (int j = t; j <= Nn; j += 256) s_v[j] = 0.0;
    if (PF && wave == 0) prefetch_row(cb, &s_dump[0][0]);   // head row of i=1
    __syncthreads();

    double vv[8];                       // scan copies of v for my 8 cols (8t+1+k)
    #pragma unroll
    for (int k = 0; k < 8; ++k) vv[k] = 0.0;
    double my_u = 0.0;                  // u[lane+1], replicated per wave
    int my_col = 0;                     // col assigned to row lane+1 (0 = none)
    int par = 0;

    for (int i = 1; i <= Mm; ++i) {
        int T = 0;
        int fj = 0;                     // col entered this iteration (0 = virtual)
        int i0 = i;                     // row to scan
        int my_pos = -1;                // my row's position in this chain

        for (;;) {
            if (t == 0) s_j[T] = fj;
            if (fj && ((fj - 1) >> 3) == t) vv[(fj - 1) & 7] = -INF; // mark used
            if (lane + 1 == i0) my_pos = T;

            const double u0 = __shfl(my_u, i0 - 1, 64);
            const float* __restrict__ row = cb + (long)(i0 - 1) * RS;

            double cur[8];
            if (CS == 1) {
                const float4 c0 = *(const float4*)(row + (t << 3));
                const float4 c1 = *(const float4*)(row + (t << 3) + 4);
                cur[0] = ((double)c0.x - u0) - vv[0];
                cur[1] = ((double)c0.y - u0) - vv[1];
                cur[2] = ((double)c0.z - u0) - vv[2];
                cur[3] = ((double)c0.w - u0) - vv[3];
                cur[4] = ((double)c1.x - u0) - vv[4];
                cur[5] = ((double)c1.y - u0) - vv[5];
                cur[6] = ((double)c1.z - u0) - vv[6];
                cur[7] = ((double)c1.w - u0) - vv[7];
            } else {
                #pragma unroll
                for (int k = 0; k < 8; ++k) {
                    const float c = row[(long)((t << 3) + k) * CS];
                    cur[k] = ((double)c - u0) - vv[k];
                }
            }
            // in-thread tournament; strict < keeps left (lower j) on ties
            double v01 = cur[0]; int k01 = 0;
            if (cur[1] < v01) { v01 = cur[1]; k01 = 1; }
            double v23 = cur[2]; int k23 = 2;
            if (cur[3] < v23) { v23 = cur[3]; k23 = 3; }
            double v45 = cur[4]; int k45 = 4;
            if (cur[5] < v45) { v45 = cur[5]; k45 = 5; }
            double v67 = cur[6]; int k67 = 6;
            if (cur[7] < v67) { v67 = cur[7]; k67 = 7; }
            if (v23 < v01) { v01 = v23; k01 = k23; }
            if (v67 < v45) { v45 = v67; k45 = k67; }
            if (v45 < v01) { v01 = v45; k01 = k45; }
            double bv = v01;
            int bj = (t << 3) + 1 + k01;

            DPP_MERGE(0x111)   // row_shr:1
            DPP_MERGE(0x112)   // row_shr:2
            DPP_MERGE(0x114)   // row_shr:4
            DPP_MERGE(0x118)   // row_shr:8
            DPP_MERGE(0x142)   // row_bcast:15
            DPP_MERGE(0x143)   // row_bcast:31
            if (lane == 63) { s_part[par][wave].v = bv; s_part[par][wave].j = bj; }

            if (PF) {
                // Speculative: warm the candidate next row (winner's is right).
                const int fjw = __builtin_amdgcn_readlane(bj, 63);
                const unsigned long long mw = __ballot(my_col == fjw);
                if (mw != 0ULL)
                    prefetch_row(cb + (long)__builtin_ctzll(mw) * RS, &s_dump[wave][0]);
            }
            barrier_lgkm();              // lgkm-only: prefetch stays in flight

            Pt pa = s_part[par][0];
            double fv = pa.v; fj = pa.j;
            #pragma unroll
            for (int w = 1; w < 4; ++w) {
                const Pt pb_ = s_part[par][w];
                if (pb_.v < fv || (pb_.v == fv && pb_.j < fj)) { fv = pb_.v; fj = pb_.j; }
            }
            if (t == 0) s_delta[T] = fv;
            T++; par ^= 1;

            const unsigned long long m = __ballot(my_col == fj); // p[fj] lookup
            if (m == 0ULL) {                              // free col -> chain done
                if (PF && i < Mm && wave == 0)
                    prefetch_row(cb + (long)i * RS, &s_dump[0][0]);  // next head row
                break;
            }
            i0 = (int)__builtin_ctzll(m) + 1;             // owning row
        }

        barrier_lgkm();   // t0's s_delta/s_j visible to all waves
        // u[row at chain pos q] += delta_q ... delta_{T-1} (sequential = ref)
        if (my_pos >= 0) {
            double au = my_u;
            for (int k = my_pos; k < T; ++k) au += s_delta[k];
            my_u = au;
        }
        // v[col entered at pos q] -= delta_q ... (sequential = ref); skip j=0
        if (t < T) {
            const int jq = s_j[t];
            if (jq) {
                double nv = s_v[jq];
                for (int k = t; k < T; ++k) nv -= s_delta[k];
                s_v[jq] = nv;
            }
        }
        if (lane == i - 1) my_col = fj;                  // augment (way==0)
        barrier_lgkm();   // s_v updates visible
        #pragma unroll
        for (int k = 0; k < 8; ++k) vv[k] = s_v[(t << 3) + 1 + k]; // un-mark
    }

    // Emit row_ind (sorted pred idx) / col_ind (gt idx ordered by pred idx).
    if (t < Mm) s_c4r[t] = my_col - 1;   // wave 0: row t+1 -> 0-based pred idx
    __syncthreads();
    if (t < Mm) {
        const int my = s_c4r[t];
        int rank = 0;
        #pragma unroll 4
        for (int q = 0; q < Mm; ++q) rank += (s_c4r[q] < my);
        out_row[b * Mm + rank] = (float)my;
        out_col[b * Mm + rank] = (float)t;
    }
}

extern "C" void kernel_launch(void* const* d_in, const int* in_sizes, int n_in,
                              void* d_out, int out_size, void* d_ws, size_t ws_size,
                              hipStream_t stream) {
    const float* ps = (const float*)d_in[0];   // (64,2048,2) f32
    const float* pb = (const float*)d_in[1];   // (64,2048,4) f32
    const int*   gs = (const int*)d_in[2];     // (64,64) i32
    const float* gb = (const float*)d_in[3];   // (64,64,4) f32
    float* out = (float*)d_out;
    float* out_row = out + (size_t)Bb * Nn * Mm;          // 8388608
    float* out_col = out_row + Bb * Mm;                    // +4096

    const size_t ct_elems = (size_t)Bb * Mm * Nn;
    if (ws_size >= ct_elems * sizeof(float)) {
        float* cT = (float*)d_ws;
        cost_dual_kernel<true><<<Bb * (Nn / 64), 256, 0, stream>>>(ps, pb, gs, gb, out, cT);
        // cT[b][i][j]: row stride N, col stride 1 (coalesced), prefetch on
        hungarian_kernel<Nn, 1L, true><<<Bb, 256, 0, stream>>>(cT, out_row, out_col);
    } else {
        cost_dual_kernel<false><<<Bb * (Nn / 64), 256, 0, stream>>>(ps, pb, gs, gb, out, nullptr);
        // Fallback: read c[b][j][i] from d_out: row stride 1, col stride M
        hungarian_kernel<1L, Mm, false><<<Bb, 256, 0, stream>>>(out, out_row, out_col);
    }
}

// Round 6
// 352.739 us; speedup vs baseline: 2.4820x; 1.0599x over previous
//
#include <hip/hip_runtime.h>
#include <math.h>
#include <limits.h>

// Problem constants (from reference): B=64, N=2048 predictions, M=64 gt boxes.
#define Bb 64
#define Nn 2048
#define Mm 64

__device__ __forceinline__ float cost1(const float4 pb4, const float4 gb4,
                                       const float2 p2, const int g) {
    const float psv = (g == 0) ? p2.x : p2.y;
    float l1 = fabsf(pb4.x - gb4.x);
    l1 += fabsf(pb4.y - gb4.y);
    l1 += fabsf(pb4.z - gb4.z);
    l1 += fabsf(pb4.w - gb4.w);
    return (-psv) + l1;
}

// ---------------------------------------------------------------------------
// Dual-layout cost kernel: out[b][j][i] (B,N,M) and cT[b][i][j] (B,M,N),
// all stores float4. Grid = Bb*(Nn/64). Unchanged from R5 (absmax 0).
// ---------------------------------------------------------------------------
template<bool WRITE_T>
__global__ __launch_bounds__(256) void cost_dual_kernel(
    const float* __restrict__ ps, const float* __restrict__ pb,
    const int* __restrict__ gs, const float* __restrict__ gb,
    float* __restrict__ out, float* __restrict__ cT)
{
    const int blk = blockIdx.x;
    const int b  = blk >> 5;            // 32 tiles per batch
    const int j0 = (blk & 31) << 6;     // tile j start
    const int t  = threadIdx.x;
    const int sub = t & 15;
    const int grp = t >> 4;             // 0..15

    // ---- Layout A: out[b][j][i4..i4+3], float4 over i ----
    {
        const int i4 = sub << 2;
        const int4   g4 = ((const int4*)(gs + b * Mm))[sub];
        const float4 gbq0 = ((const float4*)gb)[b * Mm + i4 + 0];
        const float4 gbq1 = ((const float4*)gb)[b * Mm + i4 + 1];
        const float4 gbq2 = ((const float4*)gb)[b * Mm + i4 + 2];
        const float4 gbq3 = ((const float4*)gb)[b * Mm + i4 + 3];
        #pragma unroll
        for (int r = 0; r < 4; ++r) {
            const int j = j0 + grp + (r << 4);
            const float2 p2  = ((const float2*)ps)[b * Nn + j];
            const float4 pb4 = ((const float4*)pb)[b * Nn + j];
            float4 o;
            o.x = cost1(pb4, gbq0, p2, g4.x);
            o.y = cost1(pb4, gbq1, p2, g4.y);
            o.z = cost1(pb4, gbq2, p2, g4.z);
            o.w = cost1(pb4, gbq3, p2, g4.w);
            ((float4*)(out + (((size_t)b * Nn + j) << 6)))[sub] = o;
        }
    }
    // ---- Layout B: cT[b][i][j4..j4+3], float4 over j ----
    if (WRITE_T) {
        const int j4 = j0 + (sub << 2);
        const float4 pbq0 = ((const float4*)pb)[b * Nn + j4 + 0];
        const float4 pbq1 = ((const float4*)pb)[b * Nn + j4 + 1];
        const float4 pbq2 = ((const float4*)pb)[b * Nn + j4 + 2];
        const float4 pbq3 = ((const float4*)pb)[b * Nn + j4 + 3];
        const float2 psq0 = ((const float2*)ps)[b * Nn + j4 + 0];
        const float2 psq1 = ((const float2*)ps)[b * Nn + j4 + 1];
        const float2 psq2 = ((const float2*)ps)[b * Nn + j4 + 2];
        const float2 psq3 = ((const float2*)ps)[b * Nn + j4 + 3];
        #pragma unroll
        for (int r = 0; r < 4; ++r) {
            const int i = grp + (r << 4);
            const int g = gs[b * Mm + i];
            const float4 gb4 = ((const float4*)gb)[b * Mm + i];
            float4 o;
            o.x = cost1(pbq0, gb4, psq0, g);
            o.y = cost1(pbq1, gb4, psq1, g);
            o.z = cost1(pbq2, gb4, psq2, g);
            o.w = cost1(pbq3, gb4, psq3, g);
            ((float4*)(cT + (((size_t)b * Mm + i) << 11)))[j4 >> 2] = o;
        }
    }
}

// 64-lane lexicographic (value,index) min via DPP; result lands in lane 63.
#define DPP_MERGE(CTRL)                                                         \
  {                                                                             \
    const long long bb_ = __double_as_longlong(bv);                             \
    const int lo_ = __builtin_amdgcn_update_dpp(0, (int)bb_, CTRL, 0xf, 0xf, false);            \
    const int hi_ = __builtin_amdgcn_update_dpp(0x7ff00000, (int)(bb_ >> 32), CTRL, 0xf, 0xf, false); \
    const int oj_ = __builtin_amdgcn_update_dpp(0x7fffffff, bj, CTRL, 0xf, 0xf, false);         \
    const double ov_ = __longlong_as_double(((long long)hi_ << 32) | (unsigned int)lo_);        \
    if (ov_ < bv || (ov_ == bv && oj_ < bj)) { bv = ov_; bj = oj_; }            \
  }

// Barrier that drains LDS ops only (lgkmcnt=0) and leaves global/VMEM
// (speculative prefetches) in flight: vmcnt=63, expcnt=7, lgkmcnt=0 -> 0xC07F.
__device__ __forceinline__ void barrier_lgkm() {
    asm volatile("" ::: "memory");
    __builtin_amdgcn_s_waitcnt(0xC07F);
    __builtin_amdgcn_s_barrier();
    asm volatile("" ::: "memory");
}

struct alignas(16) Pt { double v; int j; int pad; };

// Touch one 8KB cost row (64 lanes x 4B at 128B stride) -> warms L1/L2.
__device__ __forceinline__ void prefetch_row(const float* rowbase, void* ldsdump) {
    const int lane = threadIdx.x & 63;
    __builtin_amdgcn_global_load_lds(
        (const __attribute__((address_space(1))) void*)(rowbase + lane * 32),
        (__attribute__((address_space(3))) void*)ldsdump, 4, 0, 0);
}

// v[j] lives at s_v[perm(j)]: owner-permuted so the row-end reload
// (vv[k] = s_v[(k<<8)+t]) hits bank 2t&31 -> 2-way aliasing (free).
__device__ __forceinline__ int vperm(int j) {          // j in [1, Nn]
    const int q = j - 1;
    return ((q & 7) << 8) + (q >> 3);
}

// ---------------------------------------------------------------------------
// Kernel 2: reference's (buggy) JV loop. One block per batch, 256 threads.
// Thread t owns cols j in [8t+1, 8t+8] (2x dwordx4 loads when CS==1).
// In-thread tournament (keep-left-on-tie = first-min), DPP wave argmin,
// one lgkm-barrier per iteration, speculative next-row prefetch.
// ---------------------------------------------------------------------------
template<long RS, long CS, bool PF>
__global__ __launch_bounds__(256) void hungarian_kernel(
    const float* __restrict__ cmat,
    float* __restrict__ out_row, float* __restrict__ out_col)
{
    __shared__ double s_v[Nn];          // true col potentials, PERMUTED layout
    __shared__ double s_delta[Mm + 8];  // delta per chain iteration
    __shared__ int    s_j[Mm + 8];      // col entered per chain iteration
    __shared__ Pt     s_part[2][4];     // per-wave argmin partials (parity buf)
    __shared__ int    s_c4r[Mm];
    __shared__ float  s_dump[4][64];    // prefetch dump (never read)

    const int b = blockIdx.x;
    const int t = threadIdx.x;
    const int lane = t & 63;
    const int wave = t >> 6;
    const float* __restrict__ cb = cmat + (long)b * ((long)Mm * Nn);
    const double INF = __builtin_inf();

    for (int j = t; j < Nn; j += 256) s_v[j] = 0.0;
    if (PF && wave == 0) prefetch_row(cb, &s_dump[0][0]);   // head row of i=1
    __syncthreads();

    double vv[8];                       // scan copies of v for my 8 cols (8t+1+k)
    #pragma unroll
    for (int k = 0; k < 8; ++k) vv[k] = 0.0;
    double my_u = 0.0;                  // u[lane+1], replicated per wave
    int my_col = 0;                     // col assigned to row lane+1 (0 = none)
    int par = 0;

    for (int i = 1; i <= Mm; ++i) {
        int T = 0;
        int fj = 0;                     // col entered this iteration (0 = virtual)
        int i0 = i;                     // row to scan
        int my_pos = -1;                // my row's position in this chain

        for (;;) {
            if (t == 0) s_j[T] = fj;
            if (fj && ((fj - 1) >> 3) == t) vv[(fj - 1) & 7] = -INF; // mark used
            if (lane + 1 == i0) my_pos = T;

            const double u0 = __shfl(my_u, i0 - 1, 64);
            const float* __restrict__ row = cb + (long)(i0 - 1) * RS;

            double cur[8];
            if (CS == 1) {
                const float4 c0 = *(const float4*)(row + (t << 3));
                const float4 c1 = *(const float4*)(row + (t << 3) + 4);
                cur[0] = ((double)c0.x - u0) - vv[0];
                cur[1] = ((double)c0.y - u0) - vv[1];
                cur[2] = ((double)c0.z - u0) - vv[2];
                cur[3] = ((double)c0.w - u0) - vv[3];
                cur[4] = ((double)c1.x - u0) - vv[4];
                cur[5] = ((double)c1.y - u0) - vv[5];
                cur[6] = ((double)c1.z - u0) - vv[6];
                cur[7] = ((double)c1.w - u0) - vv[7];
            } else {
                #pragma unroll
                for (int k = 0; k < 8; ++k) {
                    const float c = row[(long)((t << 3) + k) * CS];
                    cur[k] = ((double)c - u0) - vv[k];
                }
            }
            // in-thread tournament; strict < keeps left (lower j) on ties
            double v01 = cur[0]; int k01 = 0;
            if (cur[1] < v01) { v01 = cur[1]; k01 = 1; }
            double v23 = cur[2]; int k23 = 2;
            if (cur[3] < v23) { v23 = cur[3]; k23 = 3; }
            double v45 = cur[4]; int k45 = 4;
            if (cur[5] < v45) { v45 = cur[5]; k45 = 5; }
            double v67 = cur[6]; int k67 = 6;
            if (cur[7] < v67) { v67 = cur[7]; k67 = 7; }
            if (v23 < v01) { v01 = v23; k01 = k23; }
            if (v67 < v45) { v45 = v67; k45 = k67; }
            if (v45 < v01) { v01 = v45; k01 = k45; }
            double bv = v01;
            int bj = (t << 3) + 1 + k01;

            DPP_MERGE(0x111)   // row_shr:1
            DPP_MERGE(0x112)   // row_shr:2
            DPP_MERGE(0x114)   // row_shr:4
            DPP_MERGE(0x118)   // row_shr:8
            DPP_MERGE(0x142)   // row_bcast:15
            DPP_MERGE(0x143)   // row_bcast:31
            if (lane == 63) { s_part[par][wave].v = bv; s_part[par][wave].j = bj; }

            if (PF) {
                // Speculative: warm the candidate next row (winner's is right).
                const int fjw = __builtin_amdgcn_readlane(bj, 63);
                const unsigned long long mw = __ballot(my_col == fjw);
                if (mw != 0ULL)
                    prefetch_row(cb + (long)__builtin_ctzll(mw) * RS, &s_dump[wave][0]);
            }
            barrier_lgkm();              // lgkm-only: prefetch stays in flight

            Pt pa = s_part[par][0];
            double fv = pa.v; fj = pa.j;
            #pragma unroll
            for (int w = 1; w < 4; ++w) {
                const Pt pb_ = s_part[par][w];
                if (pb_.v < fv || (pb_.v == fv && pb_.j < fj)) { fv = pb_.v; fj = pb_.j; }
            }
            if (t == 0) s_delta[T] = fv;
            T++; par ^= 1;

            const unsigned long long m = __ballot(my_col == fj); // p[fj] lookup
            if (m == 0ULL) {                              // free col -> chain done
                if (PF && i < Mm && wave == 0)
                    prefetch_row(cb + (long)i * RS, &s_dump[0][0]);  // next head row
                break;
            }
            i0 = (int)__builtin_ctzll(m) + 1;             // owning row
        }

        barrier_lgkm();   // t0's s_delta/s_j visible to all waves
        // u[row at chain pos q] += delta_q ... delta_{T-1} (sequential = ref)
        if (my_pos >= 0) {
            double au = my_u;
            for (int k = my_pos; k < T; ++k) au += s_delta[k];
            my_u = au;
        }
        // v[col entered at pos q] -= delta_q ... (sequential = ref); skip j=0
        if (t < T) {
            const int jq = s_j[t];
            if (jq) {
                const int idx = vperm(jq);
                double nv = s_v[idx];
                for (int k = t; k < T; ++k) nv -= s_delta[k];
                s_v[idx] = nv;
            }
        }
        if (lane == i - 1) my_col = fj;                  // augment (way==0)
        barrier_lgkm();   // s_v updates visible
        #pragma unroll
        for (int k = 0; k < 8; ++k) vv[k] = s_v[(k << 8) + t]; // un-mark (2-way banks)
    }

    // Emit row_ind (sorted pred idx) / col_ind (gt idx ordered by pred idx).
    if (t < Mm) s_c4r[t] = my_col - 1;   // wave 0: row t+1 -> 0-based pred idx
    __syncthreads();
    if (t < Mm) {
        const int my = s_c4r[t];
        int rank = 0;
        #pragma unroll 4
        for (int q = 0; q < Mm; ++q) rank += (s_c4r[q] < my);
        out_row[b * Mm + rank] = (float)my;
        out_col[b * Mm + rank] = (float)t;
    }
}

extern "C" void kernel_launch(void* const* d_in, const int* in_sizes, int n_in,
                              void* d_out, int out_size, void* d_ws, size_t ws_size,
                              hipStream_t stream) {
    const float* ps = (const float*)d_in[0];   // (64,2048,2) f32
    const float* pb = (const float*)d_in[1];   // (64,2048,4) f32
    const int*   gs = (const int*)d_in[2];     // (64,64) i32
    const float* gb = (const float*)d_in[3];   // (64,64,4) f32
    float* out = (float*)d_out;
    float* out_row = out + (size_t)Bb * Nn * Mm;          // 8388608
    float* out_col = out_row + Bb * Mm;                    // +4096

    const size_t ct_elems = (size_t)Bb * Mm * Nn;
    if (ws_size >= ct_elems * sizeof(float)) {
        float* cT = (float*)d_ws;
        cost_dual_kernel<true><<<Bb * (Nn / 64), 256, 0, stream>>>(ps, pb, gs, gb, out, cT);
        // cT[b][i][j]: row stride N, col stride 1 (coalesced), prefetch on
        hungarian_kernel<Nn, 1L, true><<<Bb, 256, 0, stream>>>(cT, out_row, out_col);
    } else {
        cost_dual_kernel<false><<<Bb * (Nn / 64), 256, 0, stream>>>(ps, pb, gs, gb, out, nullptr);
        // Fallback: read c[b][j][i] from d_out: row stride 1, col stride M
        hungarian_kernel<1L, Mm, false><<<Bb, 256, 0, stream>>>(out, out_row, out_col);
    }
}

// Round 7
// 346.932 us; speedup vs baseline: 2.5235x; 1.0167x over previous
//
#include <hip/hip_runtime.h>
#include <math.h>
#include <limits.h>

// Problem constants (from reference): B=64, N=2048 predictions, M=64 gt boxes.
#define Bb 64
#define Nn 2048
#define Mm 64

__device__ __forceinline__ float cost1(const float4 pb4, const float4 gb4,
                                       const float2 p2, const int g) {
    const float psv = (g == 0) ? p2.x : p2.y;
    float l1 = fabsf(pb4.x - gb4.x);
    l1 += fabsf(pb4.y - gb4.y);
    l1 += fabsf(pb4.z - gb4.z);
    l1 += fabsf(pb4.w - gb4.w);
    return (-psv) + l1;
}

// ---------------------------------------------------------------------------
// Dual-layout cost kernel: out[b][j][i] (B,N,M) and cT[b][i][j] (B,M,N),
// all stores float4. Grid = Bb*(Nn/64). Unchanged from R5/R6 (absmax 0).
// ---------------------------------------------------------------------------
template<bool WRITE_T>
__global__ __launch_bounds__(256) void cost_dual_kernel(
    const float* __restrict__ ps, const float* __restrict__ pb,
    const int* __restrict__ gs, const float* __restrict__ gb,
    float* __restrict__ out, float* __restrict__ cT)
{
    const int blk = blockIdx.x;
    const int b  = blk >> 5;            // 32 tiles per batch
    const int j0 = (blk & 31) << 6;     // tile j start
    const int t  = threadIdx.x;
    const int sub = t & 15;
    const int grp = t >> 4;             // 0..15

    // ---- Layout A: out[b][j][i4..i4+3], float4 over i ----
    {
        const int i4 = sub << 2;
        const int4   g4 = ((const int4*)(gs + b * Mm))[sub];
        const float4 gbq0 = ((const float4*)gb)[b * Mm + i4 + 0];
        const float4 gbq1 = ((const float4*)gb)[b * Mm + i4 + 1];
        const float4 gbq2 = ((const float4*)gb)[b * Mm + i4 + 2];
        const float4 gbq3 = ((const float4*)gb)[b * Mm + i4 + 3];
        #pragma unroll
        for (int r = 0; r < 4; ++r) {
            const int j = j0 + grp + (r << 4);
            const float2 p2  = ((const float2*)ps)[b * Nn + j];
            const float4 pb4 = ((const float4*)pb)[b * Nn + j];
            float4 o;
            o.x = cost1(pb4, gbq0, p2, g4.x);
            o.y = cost1(pb4, gbq1, p2, g4.y);
            o.z = cost1(pb4, gbq2, p2, g4.z);
            o.w = cost1(pb4, gbq3, p2, g4.w);
            ((float4*)(out + (((size_t)b * Nn + j) << 6)))[sub] = o;
        }
    }
    // ---- Layout B: cT[b][i][j4..j4+3], float4 over j ----
    if (WRITE_T) {
        const int j4 = j0 + (sub << 2);
        const float4 pbq0 = ((const float4*)pb)[b * Nn + j4 + 0];
        const float4 pbq1 = ((const float4*)pb)[b * Nn + j4 + 1];
        const float4 pbq2 = ((const float4*)pb)[b * Nn + j4 + 2];
        const float4 pbq3 = ((const float4*)pb)[b * Nn + j4 + 3];
        const float2 psq0 = ((const float2*)ps)[b * Nn + j4 + 0];
        const float2 psq1 = ((const float2*)ps)[b * Nn + j4 + 1];
        const float2 psq2 = ((const float2*)ps)[b * Nn + j4 + 2];
        const float2 psq3 = ((const float2*)ps)[b * Nn + j4 + 3];
        #pragma unroll
        for (int r = 0; r < 4; ++r) {
            const int i = grp + (r << 4);
            const int g = gs[b * Mm + i];
            const float4 gb4 = ((const float4*)gb)[b * Mm + i];
            float4 o;
            o.x = cost1(pbq0, gb4, psq0, g);
            o.y = cost1(pbq1, gb4, psq1, g);
            o.z = cost1(pbq2, gb4, psq2, g);
            o.w = cost1(pbq3, gb4, psq3, g);
            ((float4*)(cT + (((size_t)b * Mm + i) << 11)))[j4 >> 2] = o;
        }
    }
}

// 64-lane lexicographic (value,index) min via DPP; result lands in lane 63.
#define DPP_MERGE(CTRL)                                                         \
  {                                                                             \
    const long long bb_ = __double_as_longlong(bv);                             \
    const int lo_ = __builtin_amdgcn_update_dpp(0, (int)bb_, CTRL, 0xf, 0xf, false);            \
    const int hi_ = __builtin_amdgcn_update_dpp(0x7ff00000, (int)(bb_ >> 32), CTRL, 0xf, 0xf, false); \
    const int oj_ = __builtin_amdgcn_update_dpp(0x7fffffff, bj, CTRL, 0xf, 0xf, false);         \
    const double ov_ = __longlong_as_double(((long long)hi_ << 32) | (unsigned int)lo_);        \
    if (ov_ < bv || (ov_ == bv && oj_ < bj)) { bv = ov_; bj = oj_; }            \
  }

// Barrier that drains LDS ops only (lgkmcnt=0) and leaves global/VMEM
// (speculative prefetches) in flight: vmcnt=63, expcnt=7, lgkmcnt=0 -> 0xC07F.
__device__ __forceinline__ void barrier_lgkm() {
    asm volatile("" ::: "memory");
    __builtin_amdgcn_s_waitcnt(0xC07F);
    __builtin_amdgcn_s_barrier();
    asm volatile("" ::: "memory");
}

// Partial: candidate value/col AND pre-resolved owner row (0 = col free).
struct alignas(16) Pt { double v; int j; int i0; };

// Touch one 8KB cost row (64 lanes x 4B at 128B stride) -> warms L1/L2.
__device__ __forceinline__ void prefetch_row(const float* rowbase, void* ldsdump) {
    const int lane = threadIdx.x & 63;
    __builtin_amdgcn_global_load_lds(
        (const __attribute__((address_space(1))) void*)(rowbase + lane * 32),
        (__attribute__((address_space(3))) void*)ldsdump, 4, 0, 0);
}

// v[j] lives at s_v[perm(j)]: owner-permuted so the row-end reload
// (vv[k] = s_v[(k<<8)+t]) hits bank 2t&31 -> 2-way aliasing (free).
__device__ __forceinline__ int vperm(int j) {          // j in [1, Nn]
    const int q = j - 1;
    return ((q & 7) << 8) + (q >> 3);
}

// ---------------------------------------------------------------------------
// Kernel 2: reference's (buggy) JV loop. One block per batch, 256 threads.
// Thread t owns cols j in [8t+1, 8t+8] (2x dwordx4 loads when CS==1).
// Owner-row resolution (ballot+ctz) done PRE-barrier per wave and packed in
// the partial; post-barrier path = 4 ds_read_b128 -> merge -> loads (u0 shfl
// hidden under load latency). One lgkm-only barrier per chain iteration.
// ---------------------------------------------------------------------------
template<long RS, long CS, bool PF>
__global__ __launch_bounds__(256) void hungarian_kernel(
    const float* __restrict__ cmat,
    float* __restrict__ out_row, float* __restrict__ out_col)
{
    __shared__ double s_v[Nn];          // true col potentials, PERMUTED layout
    __shared__ double s_delta[Mm + 8];  // delta per chain iteration
    __shared__ int    s_j[Mm + 8];      // col entered per chain iteration
    __shared__ Pt     s_part[2][4];     // per-wave partials (parity buf)
    __shared__ int    s_c4r[Mm];
    __shared__ float  s_dump[4][64];    // prefetch dump (never read)

    const int b = blockIdx.x;
    const int t = threadIdx.x;
    const int lane = t & 63;
    const int wave = t >> 6;
    const float* __restrict__ cb = cmat + (long)b * ((long)Mm * Nn);
    const double INF = __builtin_inf();

    for (int j = t; j < Nn; j += 256) s_v[j] = 0.0;
    if (PF && wave == 0) prefetch_row(cb, &s_dump[0][0]);   // head row of i=1
    __syncthreads();

    double vv[8];                       // scan copies of v for my 8 cols (8t+1+k)
    #pragma unroll
    for (int k = 0; k < 8; ++k) vv[k] = 0.0;
    double my_u = 0.0;                  // u[lane+1], replicated per wave
    int my_col = 0;                     // col assigned to row lane+1 (0 = none)
    int par = 0;

    for (int i = 1; i <= Mm; ++i) {
        int T = 0;
        int fj = 0;                     // col entered this iteration (0 = virtual)
        int i0 = i;                     // row to scan
        int my_pos = -1;                // my row's position in this chain

        for (;;) {
            // ---- scan loads first: only depend on i0 ----
            const float* __restrict__ row = cb + (long)(i0 - 1) * RS;
            float4 c0, c1;
            float cs[8];
            if (CS == 1) {
                c0 = *(const float4*)(row + (t << 3));
                c1 = *(const float4*)(row + (t << 3) + 4);
            } else {
                #pragma unroll
                for (int k = 0; k < 8; ++k) cs[k] = row[(long)((t << 3) + k) * CS];
            }
            // u0 shuffle + bookkeeping hide under the load latency
            const double u0 = __shfl(my_u, i0 - 1, 64);
            if (t == 0) s_j[T] = fj;
            if (fj && ((fj - 1) >> 3) == t) vv[(fj - 1) & 7] = -INF; // mark used
            if (lane + 1 == i0) my_pos = T;

            double cur[8];
            if (CS == 1) {
                cur[0] = ((double)c0.x - u0) - vv[0];
                cur[1] = ((double)c0.y - u0) - vv[1];
                cur[2] = ((double)c0.z - u0) - vv[2];
                cur[3] = ((double)c0.w - u0) - vv[3];
                cur[4] = ((double)c1.x - u0) - vv[4];
                cur[5] = ((double)c1.y - u0) - vv[5];
                cur[6] = ((double)c1.z - u0) - vv[6];
                cur[7] = ((double)c1.w - u0) - vv[7];
            } else {
                #pragma unroll
                for (int k = 0; k < 8; ++k) cur[k] = ((double)cs[k] - u0) - vv[k];
            }
            // in-thread tournament; strict < keeps left (lower j) on ties
            double v01 = cur[0]; int k01 = 0;
            if (cur[1] < v01) { v01 = cur[1]; k01 = 1; }
            double v23 = cur[2]; int k23 = 2;
            if (cur[3] < v23) { v23 = cur[3]; k23 = 3; }
            double v45 = cur[4]; int k45 = 4;
            if (cur[5] < v45) { v45 = cur[5]; k45 = 5; }
            double v67 = cur[6]; int k67 = 6;
            if (cur[7] < v67) { v67 = cur[7]; k67 = 7; }
            if (v23 < v01) { v01 = v23; k01 = k23; }
            if (v67 < v45) { v45 = v67; k45 = k67; }
            if (v45 < v01) { v01 = v45; k01 = k45; }
            double bv = v01;
            int bj = (t << 3) + 1 + k01;

            DPP_MERGE(0x111)   // row_shr:1
            DPP_MERGE(0x112)   // row_shr:2
            DPP_MERGE(0x114)   // row_shr:4
            DPP_MERGE(0x118)   // row_shr:8
            DPP_MERGE(0x142)   // row_bcast:15
            DPP_MERGE(0x143)   // row_bcast:31

            // Pre-barrier owner resolution for this wave's candidate.
            const int fjw = __builtin_amdgcn_readlane(bj, 63);
            const unsigned long long mw = __ballot(my_col == fjw);
            const int i0w = mw ? (int)__builtin_ctzll(mw) + 1 : 0;
            if (lane == 63) {
                Pt p; p.v = bv; p.j = bj; p.i0 = i0w;
                s_part[par][wave] = p;
            }
            if (PF && mw != 0ULL)       // warm candidate next row (winner's is right)
                prefetch_row(cb + (long)(i0w - 1) * RS, &s_dump[wave][0]);
            barrier_lgkm();             // lgkm-only: prefetch stays in flight

            Pt pa = s_part[par][0];
            double fv = pa.v; fj = pa.j; int ni0 = pa.i0;
            #pragma unroll
            for (int w = 1; w < 4; ++w) {
                const Pt pb_ = s_part[par][w];
                if (pb_.v < fv || (pb_.v == fv && pb_.j < fj)) {
                    fv = pb_.v; fj = pb_.j; ni0 = pb_.i0;
                }
            }
            if (t == 0) s_delta[T] = fv;
            T++; par ^= 1;

            if (ni0 == 0) {                               // free col -> chain done
                if (PF && i < Mm && wave == 0)
                    prefetch_row(cb + (long)i * RS, &s_dump[0][0]);  // next head row
                break;
            }
            i0 = ni0;                                     // owning row
        }

        barrier_lgkm();   // t0's s_delta/s_j visible to all waves
        // u[row at chain pos q] += delta_q ... delta_{T-1} (sequential = ref)
        if (my_pos >= 0) {
            double au = my_u;
            for (int k = my_pos; k < T; ++k) au += s_delta[k];
            my_u = au;
        }
        // v[col entered at pos q] -= delta_q ... (sequential = ref); skip j=0
        if (t < T) {
            const int jq = s_j[t];
            if (jq) {
                const int idx = vperm(jq);
                double nv = s_v[idx];
                for (int k = t; k < T; ++k) nv -= s_delta[k];
                s_v[idx] = nv;
            }
        }
        if (lane == i - 1) my_col = fj;                  // augment (way==0)
        barrier_lgkm();   // s_v updates visible
        #pragma unroll
        for (int k = 0; k < 8; ++k) vv[k] = s_v[(k << 8) + t]; // un-mark (2-way banks)
    }

    // Emit row_ind (sorted pred idx) / col_ind (gt idx ordered by pred idx).
    if (t < Mm) s_c4r[t] = my_col - 1;   // wave 0: row t+1 -> 0-based pred idx
    __syncthreads();
    if (t < Mm) {
        const int my = s_c4r[t];
        int rank = 0;
        #pragma unroll 4
        for (int q = 0; q < Mm; ++q) rank += (s_c4r[q] < my);
        out_row[b * Mm + rank] = (float)my;
        out_col[b * Mm + rank] = (float)t;
    }
}

extern "C" void kernel_launch(void* const* d_in, const int* in_sizes, int n_in,
                              void* d_out, int out_size, void* d_ws, size_t ws_size,
                              hipStream_t stream) {
    const float* ps = (const float*)d_in[0];   // (64,2048,2) f32
    const float* pb = (const float*)d_in[1];   // (64,2048,4) f32
    const int*   gs = (const int*)d_in[2];     // (64,64) i32
    const float* gb = (const float*)d_in[3];   // (64,64,4) f32
    float* out = (float*)d_out;
    float* out_row = out + (size_t)Bb * Nn * Mm;          // 8388608
    float* out_col = out_row + Bb * Mm;                    // +4096

    const size_t ct_elems = (size_t)Bb * Mm * Nn;
    if (ws_size >= ct_elems * sizeof(float)) {
        float* cT = (float*)d_ws;
        cost_dual_kernel<true><<<Bb * (Nn / 64), 256, 0, stream>>>(ps, pb, gs, gb, out, cT);
        // cT[b][i][j]: row stride N, col stride 1 (coalesced), prefetch on
        hungarian_kernel<Nn, 1L, true><<<Bb, 256, 0, stream>>>(cT, out_row, out_col);
    } else {
        cost_dual_kernel<false><<<Bb * (Nn / 64), 256, 0, stream>>>(ps, pb, gs, gb, out, nullptr);
        // Fallback: read c[b][j][i] from d_out: row stride 1, col stride M
        hungarian_kernel<1L, Mm, false><<<Bb, 256, 0, stream>>>(out, out_row, out_col);
    }
}

// Round 8
// 333.638 us; speedup vs baseline: 2.6241x; 1.0398x over previous
//
#include <hip/hip_runtime.h>
#include <math.h>
#include <limits.h>

// Problem constants (from reference): B=64, N=2048 predictions, M=64 gt boxes.
#define Bb 64
#define Nn 2048
#define Mm 64

__device__ __forceinline__ float cost1(const float4 pb4, const float4 gb4,
                                       const float2 p2, const int g) {
    const float psv = (g == 0) ? p2.x : p2.y;
    float l1 = fabsf(pb4.x - gb4.x);
    l1 += fabsf(pb4.y - gb4.y);
    l1 += fabsf(pb4.z - gb4.z);
    l1 += fabsf(pb4.w - gb4.w);
    return (-psv) + l1;
}

// ---------------------------------------------------------------------------
// Layout-A cost tile: out[b][j][i] (B,N,M), float4 stores. blk in [0, Bb*32).
// Identical float expression to rounds 1-7 (absmax 0).
// ---------------------------------------------------------------------------
__device__ __forceinline__ void cost_tileA(
    int blk, const float* __restrict__ ps, const float* __restrict__ pb,
    const int* __restrict__ gs, const float* __restrict__ gb,
    float* __restrict__ out)
{
    const int b  = blk >> 5;            // 32 tiles per batch
    const int j0 = (blk & 31) << 6;     // tile j start
    const int t  = threadIdx.x;
    const int sub = t & 15;
    const int grp = t >> 4;             // 0..15

    const int i4 = sub << 2;
    const int4   g4 = ((const int4*)(gs + b * Mm))[sub];
    const float4 gbq0 = ((const float4*)gb)[b * Mm + i4 + 0];
    const float4 gbq1 = ((const float4*)gb)[b * Mm + i4 + 1];
    const float4 gbq2 = ((const float4*)gb)[b * Mm + i4 + 2];
    const float4 gbq3 = ((const float4*)gb)[b * Mm + i4 + 3];
    #pragma unroll
    for (int r = 0; r < 4; ++r) {
        const int j = j0 + grp + (r << 4);
        const float2 p2  = ((const float2*)ps)[b * Nn + j];
        const float4 pb4 = ((const float4*)pb)[b * Nn + j];
        float4 o;
        o.x = cost1(pb4, gbq0, p2, g4.x);
        o.y = cost1(pb4, gbq1, p2, g4.y);
        o.z = cost1(pb4, gbq2, p2, g4.z);
        o.w = cost1(pb4, gbq3, p2, g4.w);
        ((float4*)(out + (((size_t)b * Nn + j) << 6)))[sub] = o;
    }
}

// Value-only 64-lane f64 min via DPP; result lands in lane 63.
// Invalid source lanes receive +inf via update_dpp's `old` operand.
#define MIN_DPP(CTRL)                                                           \
  {                                                                             \
    const long long mb_ = __double_as_longlong(mv);                             \
    const int lo_ = __builtin_amdgcn_update_dpp(0, (int)mb_, CTRL, 0xf, 0xf, false);            \
    const int hi_ = __builtin_amdgcn_update_dpp(0x7ff00000, (int)(mb_ >> 32), CTRL, 0xf, 0xf, false); \
    const double om_ = __longlong_as_double(((long long)hi_ << 32) | (unsigned int)lo_);        \
    mv = fmin(mv, om_);                                                         \
  }

__device__ __forceinline__ double readlane_f64(double x, int l) {
    const long long v = __double_as_longlong(x);
    const int lo = __builtin_amdgcn_readlane((int)v, l);
    const int hi = __builtin_amdgcn_readlane((int)(v >> 32), l);
    return __longlong_as_double(((long long)hi << 32) | (unsigned int)lo);
}

// Barrier that drains LDS ops only (lgkmcnt=0) and leaves global/VMEM
// (speculative prefetches) in flight: vmcnt=63, expcnt=7, lgkmcnt=0 -> 0xC07F.
__device__ __forceinline__ void barrier_lgkm() {
    asm volatile("" ::: "memory");
    __builtin_amdgcn_s_waitcnt(0xC07F);
    __builtin_amdgcn_s_barrier();
    asm volatile("" ::: "memory");
}

// Partial: candidate value/col AND pre-resolved owner row (0 = col free).
struct alignas(16) Pt { double v; int j; int i0; };

// Touch one 8KB cost row (64 lanes x 4B at 128B stride) -> warms L1/L2.
__device__ __forceinline__ void prefetch_row(const float* rowbase, void* ldsdump) {
    const int lane = threadIdx.x & 63;
    __builtin_amdgcn_global_load_lds(
        (const __attribute__((address_space(1))) void*)(rowbase + lane * 32),
        (__attribute__((address_space(3))) void*)ldsdump, 4, 0, 0);
}

// v[j] lives at s_v[perm(j)]: owner-permuted so the row-end reload
// (vv[k] = s_v[(k<<8)+t]) hits bank 2t&31 -> 2-way aliasing (free).
__device__ __forceinline__ int vperm(int j) {          // j in [1, Nn]
    const int q = j - 1;
    return ((q & 7) << 8) + (q >> 3);
}

// ---------------------------------------------------------------------------
// Fused kernel. FUSED=true: grid = Bb + Bb*32 blocks; blocks [0,Bb) run the
// (buggy-JV) reference loop, each computing its own cT slice in a prologue;
// blocks [Bb, ...) write the layout-A cost output. FUSED=false: grid = Bb,
// hungarian only, reading strided from `out` (fallback, no workspace).
// ---------------------------------------------------------------------------
template<bool FUSED>
__global__ __launch_bounds__(256) void hungarian_fused(
    const float* __restrict__ ps, const float* __restrict__ pb,
    const int* __restrict__ gs, const float* __restrict__ gb,
    float* __restrict__ out, float* __restrict__ cT,
    float* __restrict__ out_row, float* __restrict__ out_col)
{
    const int bid = blockIdx.x;
    if (FUSED && bid >= Bb) {               // cost-output role
        cost_tileA(bid - Bb, ps, pb, gs, gb, out);
        return;
    }

    __shared__ double s_v[Nn];              // col potentials, PERMUTED layout
    __shared__ double s_delta[Mm + 8];      // delta per chain iteration
    __shared__ int    s_j[Mm + 8];          // col entered per chain iteration
    __shared__ Pt     s_part[2][4];         // per-wave partials (parity buf)
    __shared__ int    s_c4r[Mm];
    __shared__ float  s_dump[4][64];        // prefetch dump (never read)
    __shared__ int    s_gsv[Mm];
    __shared__ float4 s_gbv[Mm];

    const int b = bid;
    const int t = threadIdx.x;
    const int lane = t & 63;
    const int wave = t >> 6;
    constexpr long RS = FUSED ? (long)Nn : 1L;
    constexpr long CS = FUSED ? 1L : (long)Mm;
    float* __restrict__ cTb = FUSED ? (cT + (long)b * Mm * Nn) : nullptr;
    const float* __restrict__ cb =
        FUSED ? (cT + (long)b * Mm * Nn) : (out + (long)b * Nn * Mm);
    const double INF = __builtin_inf();

    for (int j = t; j < Nn; j += 256) s_v[j] = 0.0;

    if (FUSED) {
        // ---- prologue: compute this batch's cT[i][j] slice (coalesced) ----
        const float2* psb = (const float2*)(ps + (size_t)b * Nn * 2);
        const float4* pbb = (const float4*)(pb + (size_t)b * Nn * 4);
        if (t < Mm) {
            s_gsv[t] = gs[b * Mm + t];
            s_gbv[t] = ((const float4*)gb)[b * Mm + t];
        }
        float4 P[8]; float2 S[8];
        #pragma unroll
        for (int r = 0; r < 8; ++r) {
            P[r] = pbb[(t << 3) + r];
            S[r] = psb[(t << 3) + r];
        }
        __syncthreads();
        #pragma unroll 4
        for (int i = 0; i < Mm; ++i) {
            const int g = s_gsv[i];
            const float4 gb4 = s_gbv[i];
            float4 o0, o1;
            o0.x = cost1(P[0], gb4, S[0], g);
            o0.y = cost1(P[1], gb4, S[1], g);
            o0.z = cost1(P[2], gb4, S[2], g);
            o0.w = cost1(P[3], gb4, S[3], g);
            o1.x = cost1(P[4], gb4, S[4], g);
            o1.y = cost1(P[5], gb4, S[5], g);
            o1.z = cost1(P[6], gb4, S[6], g);
            o1.w = cost1(P[7], gb4, S[7], g);
            float4* dst = (float4*)(cTb + (long)i * Nn + (t << 3));
            dst[0] = o0; dst[1] = o1;
        }
        asm volatile("s_waitcnt vmcnt(0)" ::: "memory");  // own writes visible
        __syncthreads();
        if (wave == 0) prefetch_row(cb, &s_dump[0][0]);   // head row of i=1
    } else {
        __syncthreads();
    }

    double vv[8];                       // scan copies of v for my 8 cols (8t+1+k)
    #pragma unroll
    for (int k = 0; k < 8; ++k) vv[k] = 0.0;
    double my_u = 0.0;                  // u[lane+1], replicated per wave
    int my_col = 0;                     // col assigned to row lane+1 (0 = none)
    int par = 0;

    for (int i = 1; i <= Mm; ++i) {
        int T = 0;
        int fj = 0;                     // col entered this iteration (0 = virtual)
        int i0 = i;                     // row to scan
        int my_pos = -1;                // my row's position in this chain

        for (;;) {
            // ---- scan loads first: only depend on i0 ----
            const float* __restrict__ row = cb + (long)(i0 - 1) * RS;
            float4 c0, c1;
            float cs[8];
            if (CS == 1) {
                c0 = *(const float4*)(row + (t << 3));
                c1 = *(const float4*)(row + (t << 3) + 4);
            } else {
                #pragma unroll
                for (int k = 0; k < 8; ++k) cs[k] = row[(long)((t << 3) + k) * CS];
            }
            // u0 shuffle + bookkeeping hide under the load latency
            const double u0 = __shfl(my_u, i0 - 1, 64);
            if (t == 0) s_j[T] = fj;
            if (fj && ((fj - 1) >> 3) == t) vv[(fj - 1) & 7] = -INF; // mark used
            if (lane + 1 == i0) my_pos = T;

            double cur[8];
            if (CS == 1) {
                cur[0] = ((double)c0.x - u0) - vv[0];
                cur[1] = ((double)c0.y - u0) - vv[1];
                cur[2] = ((double)c0.z - u0) - vv[2];
                cur[3] = ((double)c0.w - u0) - vv[3];
                cur[4] = ((double)c1.x - u0) - vv[4];
                cur[5] = ((double)c1.y - u0) - vv[5];
                cur[6] = ((double)c1.z - u0) - vv[6];
                cur[7] = ((double)c1.w - u0) - vv[7];
            } else {
                #pragma unroll
                for (int k = 0; k < 8; ++k) cur[k] = ((double)cs[k] - u0) - vv[k];
            }
            // in-thread tournament; strict < keeps left (lower j) on ties
            double v01 = cur[0]; int k01 = 0;
            if (cur[1] < v01) { v01 = cur[1]; k01 = 1; }
            double v23 = cur[2]; int k23 = 2;
            if (cur[3] < v23) { v23 = cur[3]; k23 = 3; }
            double v45 = cur[4]; int k45 = 4;
            if (cur[5] < v45) { v45 = cur[5]; k45 = 5; }
            double v67 = cur[6]; int k67 = 6;
            if (cur[7] < v67) { v67 = cur[7]; k67 = 7; }
            if (v23 < v01) { v01 = v23; k01 = k23; }
            if (v67 < v45) { v45 = v67; k45 = k67; }
            if (v45 < v01) { v01 = v45; k01 = k45; }
            double bv = v01;
            int bj = (t << 3) + 1 + k01;

            // ---- two-pass wave argmin: value-only f64 min, then first lane ----
            double mv = bv;
            MIN_DPP(0x111)   // row_shr:1
            MIN_DPP(0x112)   // row_shr:2
            MIN_DPP(0x114)   // row_shr:4
            MIN_DPP(0x118)   // row_shr:8
            MIN_DPP(0x142)   // row_bcast:15
            MIN_DPP(0x143)   // row_bcast:31
            const double wmin = readlane_f64(mv, 63);
            const unsigned long long eq = __ballot(bv == wmin);
            const int l0 = (int)__builtin_ctzll(eq);   // lowest lane = lowest j
            const int bjw = __builtin_amdgcn_readlane(bj, l0);
            const double bvw = readlane_f64(bv, l0);   // exact cur[argmin]

            // Pre-barrier owner resolution for this wave's candidate.
            const unsigned long long mw = __ballot(my_col == bjw);
            const int i0w = mw ? (int)__builtin_ctzll(mw) + 1 : 0;
            if (lane == 0) {
                Pt p; p.v = bvw; p.j = bjw; p.i0 = i0w;
                s_part[par][wave] = p;
            }
            if (FUSED && mw != 0ULL)    // warm candidate next row (winner's is right)
                prefetch_row(cb + (long)(i0w - 1) * RS, &s_dump[wave][0]);
            barrier_lgkm();             // lgkm-only: prefetch stays in flight

            Pt pa = s_part[par][0];
            double fv = pa.v; fj = pa.j; int ni0 = pa.i0;
            #pragma unroll
            for (int w = 1; w < 4; ++w) {
                const Pt pb_ = s_part[par][w];
                if (pb_.v < fv || (pb_.v == fv && pb_.j < fj)) {
                    fv = pb_.v; fj = pb_.j; ni0 = pb_.i0;
                }
            }
            if (t == 0) s_delta[T] = fv;
            T++; par ^= 1;

            if (ni0 == 0) {                               // free col -> chain done
                if (FUSED && i < Mm && wave == 0)
                    prefetch_row(cb + (long)i * RS, &s_dump[0][0]);  // next head row
                break;
            }
            i0 = ni0;                                     // owning row
        }

        barrier_lgkm();   // t0's s_delta/s_j visible to all waves
        // u[row at chain pos q] += delta_q ... delta_{T-1} (sequential = ref)
        if (my_pos >= 0) {
            double au = my_u;
            for (int k = my_pos; k < T; ++k) au += s_delta[k];
            my_u = au;
        }
        // v[col entered at pos q] -= delta_q ... (sequential = ref); skip j=0
        if (t < T) {
            const int jq = s_j[t];
            if (jq) {
                const int idx = vperm(jq);
                double nv = s_v[idx];
                for (int k = t; k < T; ++k) nv -= s_delta[k];
                s_v[idx] = nv;
            }
        }
        if (lane == i - 1) my_col = fj;                  // augment (way==0)
        barrier_lgkm();   // s_v updates visible
        #pragma unroll
        for (int k = 0; k < 8; ++k) vv[k] = s_v[(k << 8) + t]; // un-mark (2-way banks)
    }

    // Emit row_ind (sorted pred idx) / col_ind (gt idx ordered by pred idx).
    if (t < Mm) s_c4r[t] = my_col - 1;   // wave 0: row t+1 -> 0-based pred idx
    __syncthreads();
    if (t < Mm) {
        const int my = s_c4r[t];
        int rank = 0;
        #pragma unroll 4
        for (int q = 0; q < Mm; ++q) rank += (s_c4r[q] < my);
        out_row[b * Mm + rank] = (float)my;
        out_col[b * Mm + rank] = (float)t;
    }
}

// Standalone layout-A cost kernel (fallback path only).
__global__ __launch_bounds__(256) void cost_kernel_A(
    const float* __restrict__ ps, const float* __restrict__ pb,
    const int* __restrict__ gs, const float* __restrict__ gb,
    float* __restrict__ out)
{
    cost_tileA(blockIdx.x, ps, pb, gs, gb, out);
}

extern "C" void kernel_launch(void* const* d_in, const int* in_sizes, int n_in,
                              void* d_out, int out_size, void* d_ws, size_t ws_size,
                              hipStream_t stream) {
    const float* ps = (const float*)d_in[0];   // (64,2048,2) f32
    const float* pb = (const float*)d_in[1];   // (64,2048,4) f32
    const int*   gs = (const int*)d_in[2];     // (64,64) i32
    const float* gb = (const float*)d_in[3];   // (64,64,4) f32
    float* out = (float*)d_out;
    float* out_row = out + (size_t)Bb * Nn * Mm;          // 8388608
    float* out_col = out_row + Bb * Mm;                    // +4096

    const size_t ct_elems = (size_t)Bb * Mm * Nn;
    if (ws_size >= ct_elems * sizeof(float)) {
        float* cT = (float*)d_ws;
        // Single fused dispatch: 64 hungarian blocks + 2048 cost blocks.
        hungarian_fused<true><<<Bb + Bb * (Nn / 64), 256, 0, stream>>>(
            ps, pb, gs, gb, out, cT, out_row, out_col);
    } else {
        cost_kernel_A<<<Bb * (Nn / 64), 256, 0, stream>>>(ps, pb, gs, gb, out);
        hungarian_fused<false><<<Bb, 256, 0, stream>>>(
            ps, pb, gs, gb, out, nullptr, out_row, out_col);
    }
}

// Round 10
// 330.602 us; speedup vs baseline: 2.6482x; 1.0092x over previous
//
#include <hip/hip_runtime.h>
#include <math.h>
#include <limits.h>

// Problem constants (from reference): B=64, N=2048 predictions, M=64 gt boxes.
#define Bb 64
#define Nn 2048
#define Mm 64

__device__ __forceinline__ float cost1(const float4 pb4, const float4 gb4,
                                       const float2 p2, const int g) {
    const float psv = (g == 0) ? p2.x : p2.y;
    float l1 = fabsf(pb4.x - gb4.x);
    l1 += fabsf(pb4.y - gb4.y);
    l1 += fabsf(pb4.z - gb4.z);
    l1 += fabsf(pb4.w - gb4.w);
    return (-psv) + l1;
}

// helper: readlane lane 63 of an f64 (two b32 readlanes)
__device__ __forceinline__ double readlane_f64_63(double x) {
    const long long v = __double_as_longlong(x);
    const int lo = __builtin_amdgcn_readlane((int)v, 63);
    const int hi = __builtin_amdgcn_readlane((int)(v >> 32), 63);
    return __longlong_as_double(((long long)hi << 32) | (unsigned int)lo);
}

// ---------------------------------------------------------------------------
// Layout-A cost tile: out[b][j][i] (B,N,M), float4 stores. blk in [0, Bb*32).
// Identical float expression to rounds 1-8 (absmax 0).
// ---------------------------------------------------------------------------
__device__ __forceinline__ void cost_tileA(
    int blk, const float* __restrict__ ps, const float* __restrict__ pb,
    const int* __restrict__ gs, const float* __restrict__ gb,
    float* __restrict__ out)
{
    const int b  = blk >> 5;            // 32 tiles per batch
    const int j0 = (blk & 31) << 6;     // tile j start
    const int t  = threadIdx.x;
    const int sub = t & 15;
    const int grp = t >> 4;             // 0..15

    const int i4 = sub << 2;
    const int4   g4 = ((const int4*)(gs + b * Mm))[sub];
    const float4 gbq0 = ((const float4*)gb)[b * Mm + i4 + 0];
    const float4 gbq1 = ((const float4*)gb)[b * Mm + i4 + 1];
    const float4 gbq2 = ((const float4*)gb)[b * Mm + i4 + 2];
    const float4 gbq3 = ((const float4*)gb)[b * Mm + i4 + 3];
    #pragma unroll
    for (int r = 0; r < 4; ++r) {
        const int j = j0 + grp + (r << 4);
        const float2 p2  = ((const float2*)ps)[b * Nn + j];
        const float4 pb4 = ((const float4*)pb)[b * Nn + j];
        float4 o;
        o.x = cost1(pb4, gbq0, p2, g4.x);
        o.y = cost1(pb4, gbq1, p2, g4.y);
        o.z = cost1(pb4, gbq2, p2, g4.z);
        o.w = cost1(pb4, gbq3, p2, g4.w);
        ((float4*)(out + (((size_t)b * Nn + j) << 6)))[sub] = o;
    }
}

// Value-only 64-lane f64 min via DPP; result lands in lane 63.
// Invalid source lanes receive +inf via update_dpp's `old` operand.
#define MIN_DPP(CTRL)                                                           \
  {                                                                             \
    const long long mb_ = __double_as_longlong(mv);                             \
    const int lo_ = __builtin_amdgcn_update_dpp(0, (int)mb_, CTRL, 0xf, 0xf, false);            \
    const int hi_ = __builtin_amdgcn_update_dpp(0x7ff00000, (int)(mb_ >> 32), CTRL, 0xf, 0xf, false); \
    const double om_ = __longlong_as_double(((long long)hi_ << 32) | (unsigned int)lo_);        \
    mv = fmin(mv, om_);                                                         \
  }

// Quad-permute lex-min compare-exchange on (fv, fj, fi0). After stages 0xB1
// ([1,0,3,2]) and 0x4E ([2,3,0,1]) every lane holds the min of its quad.
#define QUAD_MERGE(CTRL)                                                        \
  {                                                                             \
    const long long fb_ = __double_as_longlong(fv);                             \
    const int lo_ = __builtin_amdgcn_update_dpp(0, (int)fb_, CTRL, 0xf, 0xf, false);            \
    const int hi_ = __builtin_amdgcn_update_dpp(0, (int)(fb_ >> 32), CTRL, 0xf, 0xf, false);    \
    const int oj_ = __builtin_amdgcn_update_dpp(0, fj, CTRL, 0xf, 0xf, false);                  \
    const int oi_ = __builtin_amdgcn_update_dpp(0, fi0, CTRL, 0xf, 0xf, false);                 \
    const double ov_ = __longlong_as_double(((long long)hi_ << 32) | (unsigned int)lo_);        \
    if (ov_ < fv || (ov_ == fv && oj_ < fj)) { fv = ov_; fj = oj_; fi0 = oi_; } \
  }

// Barrier that drains LDS ops only (lgkmcnt=0) and leaves global/VMEM
// (speculative prefetches) in flight: vmcnt=63, expcnt=7, lgkmcnt=0 -> 0xC07F.
__device__ __forceinline__ void barrier_lgkm() {
    asm volatile("" ::: "memory");
    __builtin_amdgcn_s_waitcnt(0xC07F);
    __builtin_amdgcn_s_barrier();
    asm volatile("" ::: "memory");
}

// Partial: candidate value/col AND pre-resolved owner row (0 = col free).
struct alignas(16) Pt { double v; int j; int i0; };

// Touch one 8KB cost row (64 lanes x 4B at 128B stride) -> warms L1/L2.
__device__ __forceinline__ void prefetch_row(const float* rowbase, void* ldsdump) {
    const int lane = threadIdx.x & 63;
    __builtin_amdgcn_global_load_lds(
        (const __attribute__((address_space(1))) void*)(rowbase + lane * 32),
        (__attribute__((address_space(3))) void*)ldsdump, 4, 0, 0);
}

// v[j] lives at s_v[perm(j)]: owner-permuted so the row-end reload
// (vv[k] = s_v[(k<<8)+t]) hits bank 2t&31 -> 2-way aliasing (free).
__device__ __forceinline__ int vperm(int j) {          // j in [1, Nn]
    const int q = j - 1;
    return ((q & 7) << 8) + (q >> 3);
}

// ---------------------------------------------------------------------------
// Fused kernel. FUSED=true: grid = Bb + Bb*32 blocks; blocks [0,Bb) run the
// (buggy-JV) reference loop, each computing its own cT slice in a prologue;
// blocks [Bb, ...) write the layout-A cost output. FUSED=false: grid = Bb,
// hungarian only, reading strided from `out` (fallback, no workspace).
// ---------------------------------------------------------------------------
template<bool FUSED>
__global__ __launch_bounds__(256) void hungarian_fused(
    const float* __restrict__ ps, const float* __restrict__ pb,
    const int* __restrict__ gs, const float* __restrict__ gb,
    float* __restrict__ out, float* __restrict__ cT,
    float* __restrict__ out_row, float* __restrict__ out_col)
{
    const int bid = blockIdx.x;
    if (FUSED && bid >= Bb) {               // cost-output role
        cost_tileA(bid - Bb, ps, pb, gs, gb, out);
        return;
    }

    __shared__ double s_v[Nn];              // col potentials, PERMUTED layout
    __shared__ double s_delta[Mm + 8];      // delta per chain iteration
    __shared__ int    s_j[Mm + 8];          // col entered per chain iteration
    __shared__ Pt     s_part[2][4];         // per-wave partials (parity buf)
    __shared__ int    s_c4r[Mm];
    __shared__ float  s_dump[4][64];        // prefetch dump (never read)
    __shared__ int    s_gsv[Mm];
    __shared__ float4 s_gbv[Mm];

    const int b = bid;
    const int t = threadIdx.x;
    const int lane = t & 63;
    const int wave = t >> 6;
    constexpr long RS = FUSED ? (long)Nn : 1L;
    constexpr long CS = FUSED ? 1L : (long)Mm;
    float* __restrict__ cTb = FUSED ? (cT + (long)b * Mm * Nn) : nullptr;
    const float* __restrict__ cb =
        FUSED ? (cT + (long)b * Mm * Nn) : (out + (long)b * Nn * Mm);
    const double INF = __builtin_inf();

    for (int j = t; j < Nn; j += 256) s_v[j] = 0.0;

    if (FUSED) {
        // ---- prologue: compute this batch's cT[i][j] slice (coalesced) ----
        const float2* psb = (const float2*)(ps + (size_t)b * Nn * 2);
        const float4* pbb = (const float4*)(pb + (size_t)b * Nn * 4);
        if (t < Mm) {
            s_gsv[t] = gs[b * Mm + t];
            s_gbv[t] = ((const float4*)gb)[b * Mm + t];
        }
        float4 P[8]; float2 S[8];
        #pragma unroll
        for (int r = 0; r < 8; ++r) {
            P[r] = pbb[(t << 3) + r];
            S[r] = psb[(t << 3) + r];
        }
        __syncthreads();
        #pragma unroll 4
        for (int i = 0; i < Mm; ++i) {
            const int g = s_gsv[i];
            const float4 gb4 = s_gbv[i];
            float4 o0, o1;
            o0.x = cost1(P[0], gb4, S[0], g);
            o0.y = cost1(P[1], gb4, S[1], g);
            o0.z = cost1(P[2], gb4, S[2], g);
            o0.w = cost1(P[3], gb4, S[3], g);
            o1.x = cost1(P[4], gb4, S[4], g);
            o1.y = cost1(P[5], gb4, S[5], g);
            o1.z = cost1(P[6], gb4, S[6], g);
            o1.w = cost1(P[7], gb4, S[7], g);
            float4* dst = (float4*)(cTb + (long)i * Nn + (t << 3));
            dst[0] = o0; dst[1] = o1;
        }
        asm volatile("s_waitcnt vmcnt(0)" ::: "memory");  // own writes visible
        __syncthreads();
        if (wave == 0) prefetch_row(cb, &s_dump[0][0]);   // head row of i=1
    } else {
        __syncthreads();
    }

    double vv[8];                       // scan copies of v for my 8 cols (8t+1+k)
    #pragma unroll
    for (int k = 0; k < 8; ++k) vv[k] = 0.0;
    double my_u = 0.0;                  // u[lane+1], replicated per wave
    int my_col = 0;                     // col assigned to row lane+1 (0 = none)
    int par = 0;

    for (int i = 1; i <= Mm; ++i) {
        int T = 0;
        int fjc = 0;                    // col entered this iteration (0 = virtual)
        int i0 = i;                     // row to scan
        int my_pos = -1;                // my row's position in this chain

        for (;;) {
            // ---- scan loads first: only depend on i0 ----
            const float* __restrict__ row = cb + (long)(i0 - 1) * RS;
            float4 c0, c1;
            float cs[8];
            if (CS == 1) {
                c0 = *(const float4*)(row + (t << 3));
                c1 = *(const float4*)(row + (t << 3) + 4);
            } else {
                #pragma unroll
                for (int k = 0; k < 8; ++k) cs[k] = row[(long)((t << 3) + k) * CS];
            }
            // u0 shuffle + bookkeeping hide under the load latency
            const double u0 = __shfl(my_u, i0 - 1, 64);
            if (t == 0) s_j[T] = fjc;
            if (fjc && ((fjc - 1) >> 3) == t) vv[(fjc - 1) & 7] = -INF; // mark used
            if (lane + 1 == i0) my_pos = T;

            double cur[8];
            if (CS == 1) {
                cur[0] = ((double)c0.x - u0) - vv[0];
                cur[1] = ((double)c0.y - u0) - vv[1];
                cur[2] = ((double)c0.z - u0) - vv[2];
                cur[3] = ((double)c0.w - u0) - vv[3];
                cur[4] = ((double)c1.x - u0) - vv[4];
                cur[5] = ((double)c1.y - u0) - vv[5];
                cur[6] = ((double)c1.z - u0) - vv[6];
                cur[7] = ((double)c1.w - u0) - vv[7];
            } else {
                #pragma unroll
                for (int k = 0; k < 8; ++k) cur[k] = ((double)cs[k] - u0) - vv[k];
            }
            // in-thread tournament; strict < keeps left (lower j) on ties
            double v01 = cur[0]; int k01 = 0;
            if (cur[1] < v01) { v01 = cur[1]; k01 = 1; }
            double v23 = cur[2]; int k23 = 2;
            if (cur[3] < v23) { v23 = cur[3]; k23 = 3; }
            double v45 = cur[4]; int k45 = 4;
            if (cur[5] < v45) { v45 = cur[5]; k45 = 5; }
            double v67 = cur[6]; int k67 = 6;
            if (cur[7] < v67) { v67 = cur[7]; k67 = 7; }
            if (v23 < v01) { v01 = v23; k01 = k23; }
            if (v67 < v45) { v45 = v67; k45 = k67; }
            if (v45 < v01) { v01 = v45; k01 = k45; }
            double bv = v01;
            int bj = (t << 3) + 1 + k01;

            // ---- two-pass wave argmin: value-only f64 min, then first lane ----
            double mv = bv;
            MIN_DPP(0x111)   // row_shr:1
            MIN_DPP(0x112)   // row_shr:2
            MIN_DPP(0x114)   // row_shr:4
            MIN_DPP(0x118)   // row_shr:8
            MIN_DPP(0x142)   // row_bcast:15
            MIN_DPP(0x143)   // row_bcast:31
            const double wmin = readlane_f64_63(mv);
            const unsigned long long eq = __ballot(bv == wmin);
            const int l0 = (int)__builtin_ctzll(eq);   // lowest lane = lowest j
            const int bjw = __builtin_amdgcn_readlane(bj, l0);

            // Pre-barrier owner resolution for this wave's candidate.
            const unsigned long long mw = __ballot(my_col == bjw);
            const int i0w = mw ? (int)__builtin_ctzll(mw) + 1 : 0;
            if (lane == l0) {           // winner lane writes its exact f64 value
                Pt p; p.v = bv; p.j = bj; p.i0 = i0w;
                s_part[par][wave] = p;
            }
            if (FUSED && mw != 0ULL)    // warm candidate next row (winner's is right)
                prefetch_row(cb + (long)(i0w - 1) * RS, &s_dump[wave][0]);
            barrier_lgkm();             // lgkm-only: prefetch stays in flight

            // ---- quad-DPP cross-wave merge: lane reads partial[lane&3] ----
            const Pt pq = s_part[par][lane & 3];
            double fv = pq.v; int fj = pq.j; int fi0 = pq.i0;
            QUAD_MERGE(0xB1)   // quad_perm [1,0,3,2]
            QUAD_MERGE(0x4E)   // quad_perm [2,3,0,1]
            fjc = fj;
            if (t == 0) s_delta[T] = fv;
            T++; par ^= 1;

            if (fi0 == 0) {                               // free col -> chain done
                if (FUSED && i < Mm && wave == 0)
                    prefetch_row(cb + (long)i * RS, &s_dump[0][0]);  // next head row
                break;
            }
            i0 = fi0;                                     // owning row
        }

        barrier_lgkm();   // t0's s_delta/s_j visible to all waves
        // u[row at chain pos q] += delta_q ... delta_{T-1} (sequential = ref)
        if (my_pos >= 0) {
            double au = my_u;
            for (int k = my_pos; k < T; ++k) au += s_delta[k];
            my_u = au;
        }
        // v[col entered at pos q] -= delta_q ... (sequential = ref); skip j=0
        if (t < T) {
            const int jq = s_j[t];
            if (jq) {
                const int idx = vperm(jq);
                double nv = s_v[idx];
                for (int k = t; k < T; ++k) nv -= s_delta[k];
                s_v[idx] = nv;
            }
        }
        if (lane == i - 1) my_col = fjc;                 // augment (way==0)
        barrier_lgkm();   // s_v updates visible
        #pragma unroll
        for (int k = 0; k < 8; ++k) vv[k] = s_v[(k << 8) + t]; // un-mark (2-way banks)
    }

    // Emit row_ind (sorted pred idx) / col_ind (gt idx ordered by pred idx).
    if (t < Mm) s_c4r[t] = my_col - 1;   // wave 0: row t+1 -> 0-based pred idx
    __syncthreads();
    if (t < Mm) {
        const int my = s_c4r[t];
        int rank = 0;
        #pragma unroll 4
        for (int q = 0; q < Mm; ++q) rank += (s_c4r[q] < my);
        out_row[b * Mm + rank] = (float)my;
        out_col[b * Mm + rank] = (float)t;
    }
}

// Standalone layout-A cost kernel (fallback path only).
__global__ __launch_bounds__(256) void cost_kernel_A(
    const float* __restrict__ ps, const float* __restrict__ pb,
    const int* __restrict__ gs, const float* __restrict__ gb,
    float* __restrict__ out)
{
    cost_tileA(blockIdx.x, ps, pb, gs, gb, out);
}

extern "C" void kernel_launch(void* const* d_in, const int* in_sizes, int n_in,
                              void* d_out, int out_size, void* d_ws, size_t ws_size,
                              hipStream_t stream) {
    const float* ps = (const float*)d_in[0];   // (64,2048,2) f32
    const float* pb = (const float*)d_in[1];   // (64,2048,4) f32
    const int*   gs = (const int*)d_in[2];     // (64,64) i32
    const float* gb = (const float*)d_in[3];   // (64,64,4) f32
    float* out = (float*)d_out;
    float* out_row = out + (size_t)Bb * Nn * Mm;          // 8388608
    float* out_col = out_row + Bb * Mm;                    // +4096

    const size_t ct_elems = (size_t)Bb * Mm * Nn;
    if (ws_size >= ct_elems * sizeof(float)) {
        float* cT = (float*)d_ws;
        // Single fused dispatch: 64 hungarian blocks + 2048 cost blocks.
        hungarian_fused<true><<<Bb + Bb * (Nn / 64), 256, 0, stream>>>(
            ps, pb, gs, gb, out, cT, out_row, out_col);
    } else {
        cost_kernel_A<<<Bb * (Nn / 64), 256, 0, stream>>>(ps, pb, gs, gb, out);
        hungarian_fused<false><<<Bb, 256, 0, stream>>>(
            ps, pb, gs, gb, out, nullptr, out_row, out_col);
    }
}